// Round 4
// baseline (811.625 us; speedup 1.0000x reference)
//
#include <hip/hip_runtime.h>
#include <hip/hip_bf16.h>
#include <math.h>

// Problem constants
constexpr int B_ = 4;
constexpr int N_ = 20000;
constexpr int E_ = 320000;
constexpr int HEADS_ = 4;
constexpr int NCH = 64;                       // attention chunks per (b,head)
constexpr int CS = (N_ + NCH - 1) / NCH;      // 313
constexpr int NT_ = (B_ * N_) / 16;           // 5000 node tiles
constexpr int NTW_ = N_ / 16;                 // 1250 node tiles per batch

typedef __attribute__((ext_vector_type(8))) short short8;   // 8 bf16
typedef __attribute__((ext_vector_type(4))) float f32x4;

// Workspace layout (bytes). ~84 MB.
constexpr size_t HB = (size_t)B_ * N_ * 64 * 4;      // 20,480,000
constexpr size_t OFF_H    = 0;
constexpr size_t OFF_A1   = HB;            // tdst, later k
constexpr size_t OFF_A2   = 2 * HB;        // agg, later v
constexpr size_t OFF_CNT  = 3 * HB;                          // B*N ints
constexpr size_t OFF_POS  = OFF_CNT + (size_t)B_ * N_ * 4;   // B*N ints
constexpr size_t OFF_OFFS = OFF_POS + (size_t)B_ * N_ * 4;   // B*(N+1) ints
constexpr size_t OFF_ESRC = OFF_OFFS + ((size_t)B_ * (N_ + 1) * 4 + 64); // B*E ints
constexpr size_t OFF_EDST = OFF_ESRC + (size_t)B_ * E_ * 4;  // B*E ints
constexpr size_t OFF_HB16 = OFF_EDST + (size_t)B_ * E_ * 4;  // B*N*64 bf16
constexpr size_t OFF_AVEC = OFF_HB16 + (size_t)B_ * N_ * 64 * 2;
constexpr size_t OFF_Q    = OFF_AVEC + 1024;
constexpr size_t OFF_CTX  = OFF_Q + 1024;
constexpr size_t OFF_WCMB = OFF_CTX + 1024;
constexpr size_t OFF_FLAG = OFF_WCMB + 1024;
constexpr size_t OFF_PART = OFF_FLAG + 64;                   // 1024*18 f partials

static __device__ __forceinline__ unsigned short f2bf(float f) {
    union { float f; unsigned u; } v; v.f = f;
    unsigned r = v.u + 0x7fffu + ((v.u >> 16) & 1u);
    return (unsigned short)(r >> 16);
}

// ---------------- mask dtype detection ----------------
__global__ void k_maskdetect(const unsigned int* __restrict__ m, int* __restrict__ flag) {
    if (blockIdx.x == 0 && threadIdx.x == 0) {
        bool alli = true, allf = true;
        for (int i = 0; i < 256; ++i) {
            unsigned v = m[i];
            alli = alli && (v <= 1u);
            allf = allf && (v == 0u || v == 0x3f800000u);
        }
        *flag = alli ? 1 : (allf ? 2 : 0);
    }
}

// ---------------- h = relu(gn @ w_node + b_node); hb16 = bf16(h) ----------------
__global__ __launch_bounds__(256) void k_embed(const float* __restrict__ gn,
                                               const float* __restrict__ w,
                                               const float* __restrict__ bias,
                                               float* __restrict__ h,
                                               unsigned short* __restrict__ hb16) {
    int lane = threadIdx.x & 63;
    float wc[16];
#pragma unroll
    for (int i = 0; i < 16; ++i) wc[i] = w[i * 64 + lane];
    float bb = bias[lane];
    int gw = (blockIdx.x * blockDim.x + threadIdx.x) >> 6;
    int nw = (gridDim.x * blockDim.x) >> 6;
    for (int node = gw; node < B_ * N_; node += nw) {
        const float* r = gn + (size_t)node * 16;
        float a0 = 0.f, a1 = 0.f, a2 = 0.f, a3 = 0.f;
#pragma unroll
        for (int i = 0; i < 16; i += 4) {
            a0 = fmaf(r[i + 0], wc[i + 0], a0);
            a1 = fmaf(r[i + 1], wc[i + 1], a1);
            a2 = fmaf(r[i + 2], wc[i + 2], a2);
            a3 = fmaf(r[i + 3], wc[i + 3], a3);
        }
        float v = fmaxf(bb + ((a0 + a1) + (a2 + a3)), 0.f);
        h[(size_t)node * 64 + lane] = v;
        hb16[(size_t)node * 64 + lane] = f2bf(v);
    }
}

// ---------------- CSR build ----------------
__global__ void k_count(const int* __restrict__ links, int* __restrict__ cnt) {
    int i = blockIdx.x * blockDim.x + threadIdx.x;
    if (i >= B_ * E_) return;
    int b = i / E_, e = i - b * E_;
    int dst = links[(size_t)b * 2 * E_ + E_ + e];
    atomicAdd(&cnt[b * N_ + dst], 1);
}

// 1024-thread shuffle-based scan, 4 barriers per 1024-chunk
__global__ __launch_bounds__(1024) void k_scan(const int* __restrict__ cnt,
                                               int* __restrict__ offs,
                                               int* __restrict__ pos) {
    __shared__ int wsum[16];
    __shared__ int sbase;
    int b = blockIdx.x, t = threadIdx.x;
    int lane = t & 63, wv = t >> 6;
    if (t == 0) { sbase = 0; offs[(size_t)b * (N_ + 1)] = 0; }
    __syncthreads();
    for (int base = 0; base < N_; base += 1024) {
        int idx = base + t;
        int c = (idx < N_) ? cnt[(size_t)b * N_ + idx] : 0;
        int x = c;
#pragma unroll
        for (int o = 1; o < 64; o <<= 1) {
            int y = __shfl_up(x, o);
            if (lane >= o) x += y;
        }
        if (lane == 63) wsum[wv] = x;
        __syncthreads();
        if (wv == 0) {
            int s = (lane < 16) ? wsum[lane] : 0;
#pragma unroll
            for (int o = 1; o < 16; o <<= 1) {
                int y = __shfl_up(s, o);
                if (lane >= o) s += y;
            }
            if (lane < 16) wsum[lane] = s;
        }
        __syncthreads();
        int wpre = (wv > 0) ? wsum[wv - 1] : 0;
        int incl = x + wpre + sbase;
        if (idx < N_) {
            offs[(size_t)b * (N_ + 1) + idx + 1] = incl;
            pos[(size_t)b * N_ + idx] = incl - c;
        }
        __syncthreads();
        if (t == 1023) sbase = incl;
        __syncthreads();
    }
}

__global__ void k_fill(const int* __restrict__ links, int* __restrict__ pos,
                       int* __restrict__ esrc, int* __restrict__ edst) {
    int i = blockIdx.x * blockDim.x + threadIdx.x;
    if (i >= B_ * E_) return;
    int b = i / E_, e = i - b * E_;
    int src = links[(size_t)b * 2 * E_ + e];
    int dst = links[(size_t)b * 2 * E_ + E_ + e];
    int slot = atomicAdd(&pos[b * N_ + dst], 1);
    esrc[(size_t)b * E_ + slot] = src;
    edst[(size_t)b * E_ + slot] = dst;
}

// ---------------- tdst = W2^T h + msg_b (MFMA node GEMM) ----------------
__global__ __launch_bounds__(256) void k_tdst_mfma(const unsigned short* __restrict__ hb16,
                                                   const float* __restrict__ mw,
                                                   const float* __restrict__ mb,
                                                   float* __restrict__ td) {
    int lane = threadIdx.x & 63;
    int g = lane >> 4, c = lane & 15;
    short8 bf[4][2];
#pragma unroll
    for (int nt = 0; nt < 4; ++nt)
#pragma unroll
        for (int ks = 0; ks < 2; ++ks)
#pragma unroll
            for (int j = 0; j < 8; ++j)
                bf[nt][ks][j] = (short)f2bf(mw[(64 + ks * 32 + g * 8 + j) * 64 + nt * 16 + c]);
    float mbv[4];
#pragma unroll
    for (int nt = 0; nt < 4; ++nt) mbv[nt] = mb[nt * 16 + c];

    int wid = blockIdx.x * 4 + (threadIdx.x >> 6);
    int nw = gridDim.x * 4;
    f32x4 zero = {0.f, 0.f, 0.f, 0.f};
    for (int t = wid; t < NT_; t += nw) {
        const unsigned short* ap = hb16 + ((size_t)t * 16 + c) * 64;
        short8 a0 = *(const short8*)(ap + g * 8);
        short8 a1 = *(const short8*)(ap + 32 + g * 8);
        f32x4 acc[4];
#pragma unroll
        for (int nt = 0; nt < 4; ++nt) {
            acc[nt] = __builtin_amdgcn_mfma_f32_16x16x32_bf16(a0, bf[nt][0], zero, 0, 0, 0);
            acc[nt] = __builtin_amdgcn_mfma_f32_16x16x32_bf16(a1, bf[nt][1], acc[nt], 0, 0, 0);
        }
#pragma unroll
        for (int r = 0; r < 4; ++r) {
            size_t row = (size_t)t * 16 + 4 * g + r;
#pragma unroll
            for (int nt = 0; nt < 4; ++nt)
                td[row * 64 + nt * 16 + c] = acc[nt][r] + mbv[nt];
        }
    }
}

// ---------------- CSR dst-owned fused MFMA edge kernel ----------------
// Wave owns 16 consecutive dst nodes; accumulates relu(W1 h_src + tdst) into
// per-wave LDS; coalesced agg write; zero atomics.
__global__ __launch_bounds__(256) void k_edge_csr(const unsigned short* __restrict__ hb16,
                                                  const float* __restrict__ td,
                                                  const int* __restrict__ offs,
                                                  const int* __restrict__ esrc,
                                                  const int* __restrict__ edst,
                                                  const float* __restrict__ mw,
                                                  float* __restrict__ agg) {
    __shared__ float lacc[4][1024];
    int lane = threadIdx.x & 63;
    int g = lane >> 4, c = lane & 15;
    int wv = threadIdx.x >> 6;
    short8 bf[4][2];
#pragma unroll
    for (int nt = 0; nt < 4; ++nt)
#pragma unroll
        for (int ks = 0; ks < 2; ++ks)
#pragma unroll
            for (int j = 0; j < 8; ++j)
                bf[nt][ks][j] = (short)f2bf(mw[(ks * 32 + g * 8 + j) * 64 + nt * 16 + c]);

    int wid = blockIdx.x * 4 + wv;       // 0 .. 4999
    int b = wid / NTW_;
    int n0 = (wid - b * NTW_) * 16;
    const int* ep = esrc + (size_t)b * E_;
    const int* dp = edst + (size_t)b * E_;
    int beg = offs[(size_t)b * (N_ + 1) + n0];
    int end = offs[(size_t)b * (N_ + 1) + n0 + 16];

    float* la = lacc[wv];
#pragma unroll
    for (int d = 0; d < 16; ++d) la[d * 64 + lane] = 0.f;

    f32x4 zero = {0.f, 0.f, 0.f, 0.f};
    for (int s0 = beg; s0 < end; s0 += 16) {
        int slotc = s0 + c;
        int src = (slotc < end) ? ep[slotc] : 0;
        const unsigned short* hrow = hb16 + ((size_t)(b * N_) + src) * 64;
        short8 a0 = *(const short8*)(hrow + g * 8);
        short8 a1 = *(const short8*)(hrow + 32 + g * 8);

        f32x4 acc[4];
#pragma unroll
        for (int nt = 0; nt < 4; ++nt) {
            acc[nt] = __builtin_amdgcn_mfma_f32_16x16x32_bf16(a0, bf[nt][0], zero, 0, 0, 0);
            acc[nt] = __builtin_amdgcn_mfma_f32_16x16x32_bf16(a1, bf[nt][1], acc[nt], 0, 0, 0);
        }

        // epilogue: row rr = 4g+r is edge slot s0+rr; add tdst (L1-hot), relu
        float val[4][4]; // [nt][r]
#pragma unroll
        for (int r = 0; r < 4; ++r) {
            int slot = s0 + 4 * g + r;
            bool ok = slot < end;
            int dsg = ok ? dp[slot] : n0;
            const float* trow = td + ((size_t)(b * N_) + dsg) * 64;
#pragma unroll
            for (int nt = 0; nt < 4; ++nt)
                val[nt][r] = ok ? fmaxf(acc[nt][r] + trow[nt * 16 + c], 0.f) : 0.f;
        }

        // segmented reduce over sorted dst runs; LDS accumulate (lane owns col=lane)
        int nrows = end - s0; if (nrows > 16) nrows = 16;
        int i = 0;
        while (i < nrows) {
            int d = dp[s0 + i];
            int j = i + 1;
            while (j < nrows && dp[s0 + j] == d) ++j;
            float s0v = 0.f, s1v = 0.f, s2v = 0.f, s3v = 0.f;
#pragma unroll
            for (int r = 0; r < 4; ++r) {
                int rr = 4 * g + r;
                bool in = (rr >= i) && (rr < j);
                s0v += in ? val[0][r] : 0.f;
                s1v += in ? val[1][r] : 0.f;
                s2v += in ? val[2][r] : 0.f;
                s3v += in ? val[3][r] : 0.f;
            }
            s0v += __shfl_xor(s0v, 16); s0v += __shfl_xor(s0v, 32);
            s1v += __shfl_xor(s1v, 16); s1v += __shfl_xor(s1v, 32);
            s2v += __shfl_xor(s2v, 16); s2v += __shfl_xor(s2v, 32);
            s3v += __shfl_xor(s3v, 16); s3v += __shfl_xor(s3v, 32);
            float outv = (g == 0) ? s0v : (g == 1) ? s1v : (g == 2) ? s2v : s3v;
            la[(d - n0) * 64 + lane] += outv;
            i = j;
        }
    }

    // coalesced write-out (covers every node -> no memset needed)
#pragma unroll
    for (int d = 0; d < 16; ++d)
        agg[((size_t)(b * N_) + n0 + d) * 64 + lane] = la[d * 64 + lane];
}

// ---------------- h += relu([h,agg] @ upd_w + upd_b) (MFMA) ----------------
__global__ __launch_bounds__(256) void k_upd_mfma(float* __restrict__ h,
                                                  unsigned short* __restrict__ hb16,
                                                  const float* __restrict__ agg,
                                                  const float* __restrict__ uw,
                                                  const float* __restrict__ ub) {
    int lane = threadIdx.x & 63;
    int g = lane >> 4, c = lane & 15;
    short8 bh[4][2], ba[4][2];
#pragma unroll
    for (int nt = 0; nt < 4; ++nt)
#pragma unroll
        for (int ks = 0; ks < 2; ++ks)
#pragma unroll
            for (int j = 0; j < 8; ++j) {
                bh[nt][ks][j] = (short)f2bf(uw[(ks * 32 + g * 8 + j) * 64 + nt * 16 + c]);
                ba[nt][ks][j] = (short)f2bf(uw[(64 + ks * 32 + g * 8 + j) * 64 + nt * 16 + c]);
            }
    float ubv[4];
#pragma unroll
    for (int nt = 0; nt < 4; ++nt) ubv[nt] = ub[nt * 16 + c];

    int wid = blockIdx.x * 4 + (threadIdx.x >> 6);
    int nw = gridDim.x * 4;
    f32x4 zero = {0.f, 0.f, 0.f, 0.f};
    for (int t = wid; t < NT_; t += nw) {
        const unsigned short* ap = hb16 + ((size_t)t * 16 + c) * 64;
        short8 a0 = *(const short8*)(ap + g * 8);
        short8 a1 = *(const short8*)(ap + 32 + g * 8);

        const float* gp = agg + ((size_t)t * 16 + c) * 64;
        float4 q0 = *(const float4*)(gp + g * 8);
        float4 q1 = *(const float4*)(gp + g * 8 + 4);
        float4 q2 = *(const float4*)(gp + 32 + g * 8);
        float4 q3 = *(const float4*)(gp + 32 + g * 8 + 4);
        short8 s0, s1;
        s0[0] = (short)f2bf(q0.x); s0[1] = (short)f2bf(q0.y);
        s0[2] = (short)f2bf(q0.z); s0[3] = (short)f2bf(q0.w);
        s0[4] = (short)f2bf(q1.x); s0[5] = (short)f2bf(q1.y);
        s0[6] = (short)f2bf(q1.z); s0[7] = (short)f2bf(q1.w);
        s1[0] = (short)f2bf(q2.x); s1[1] = (short)f2bf(q2.y);
        s1[2] = (short)f2bf(q2.z); s1[3] = (short)f2bf(q2.w);
        s1[4] = (short)f2bf(q3.x); s1[5] = (short)f2bf(q3.y);
        s1[6] = (short)f2bf(q3.z); s1[7] = (short)f2bf(q3.w);

        f32x4 acc[4];
#pragma unroll
        for (int nt = 0; nt < 4; ++nt) {
            acc[nt] = __builtin_amdgcn_mfma_f32_16x16x32_bf16(a0, bh[nt][0], zero, 0, 0, 0);
            acc[nt] = __builtin_amdgcn_mfma_f32_16x16x32_bf16(a1, bh[nt][1], acc[nt], 0, 0, 0);
            acc[nt] = __builtin_amdgcn_mfma_f32_16x16x32_bf16(s0, ba[nt][0], acc[nt], 0, 0, 0);
            acc[nt] = __builtin_amdgcn_mfma_f32_16x16x32_bf16(s1, ba[nt][1], acc[nt], 0, 0, 0);
        }
#pragma unroll
        for (int r = 0; r < 4; ++r) {
            size_t row = (size_t)t * 16 + 4 * g + r;
#pragma unroll
            for (int nt = 0; nt < 4; ++nt) {
                size_t idx = row * 64 + nt * 16 + c;
                float v = h[idx] + fmaxf(acc[nt][r] + ubv[nt], 0.f);
                h[idx] = v;
                hb16[idx] = f2bf(v);
            }
        }
    }
}

// ---------------- k/v projections (MFMA) ----------------
__global__ __launch_bounds__(256) void k_kv_mfma(const unsigned short* __restrict__ hb16,
                                                 const float* __restrict__ wk,
                                                 const float* __restrict__ bk,
                                                 const float* __restrict__ wv,
                                                 const float* __restrict__ bv,
                                                 float* __restrict__ kb,
                                                 float* __restrict__ vb) {
    int lane = threadIdx.x & 63;
    int g = lane >> 4, c = lane & 15;
    short8 bkf[4][2], bvf[4][2];
#pragma unroll
    for (int nt = 0; nt < 4; ++nt)
#pragma unroll
        for (int ks = 0; ks < 2; ++ks)
#pragma unroll
            for (int j = 0; j < 8; ++j) {
                bkf[nt][ks][j] = (short)f2bf(wk[(ks * 32 + g * 8 + j) * 64 + nt * 16 + c]);
                bvf[nt][ks][j] = (short)f2bf(wv[(ks * 32 + g * 8 + j) * 64 + nt * 16 + c]);
            }
    float bkv[4], bvv[4];
#pragma unroll
    for (int nt = 0; nt < 4; ++nt) { bkv[nt] = bk[nt * 16 + c]; bvv[nt] = bv[nt * 16 + c]; }

    int wid = blockIdx.x * 4 + (threadIdx.x >> 6);
    int nw = gridDim.x * 4;
    f32x4 zero = {0.f, 0.f, 0.f, 0.f};
    for (int t = wid; t < NT_; t += nw) {
        const unsigned short* ap = hb16 + ((size_t)t * 16 + c) * 64;
        short8 a0 = *(const short8*)(ap + g * 8);
        short8 a1 = *(const short8*)(ap + 32 + g * 8);
        f32x4 ak[4], av[4];
#pragma unroll
        for (int nt = 0; nt < 4; ++nt) {
            ak[nt] = __builtin_amdgcn_mfma_f32_16x16x32_bf16(a0, bkf[nt][0], zero, 0, 0, 0);
            ak[nt] = __builtin_amdgcn_mfma_f32_16x16x32_bf16(a1, bkf[nt][1], ak[nt], 0, 0, 0);
            av[nt] = __builtin_amdgcn_mfma_f32_16x16x32_bf16(a0, bvf[nt][0], zero, 0, 0, 0);
            av[nt] = __builtin_amdgcn_mfma_f32_16x16x32_bf16(a1, bvf[nt][1], av[nt], 0, 0, 0);
        }
#pragma unroll
        for (int r = 0; r < 4; ++r) {
            size_t row = (size_t)t * 16 + 4 * g + r;
#pragma unroll
            for (int nt = 0; nt < 4; ++nt) {
                kb[row * 64 + nt * 16 + c] = ak[nt][r] + bkv[nt];
                vb[row * 64 + nt * 16 + c] = av[nt][r] + bvv[nt];
            }
        }
    }
}

// ---------------- a = relu(ad @ w_ad + b_ad); q = a @ wq + bq ----------------
__global__ __launch_bounds__(64) void k_aq(const float* __restrict__ ad,
                                           const float* __restrict__ wad,
                                           const float* __restrict__ bad,
                                           const float* __restrict__ wq,
                                           const float* __restrict__ bq,
                                           float* __restrict__ a_out,
                                           float* __restrict__ q_out) {
    int b = blockIdx.x, t = threadIdx.x;
    __shared__ float sa[64];
    float acc = bad[t];
#pragma unroll
    for (int i = 0; i < 8; ++i) acc = fmaf(ad[b * 8 + i], wad[i * 64 + t], acc);
    float av = fmaxf(acc, 0.f);
    sa[t] = av;
    a_out[b * 64 + t] = av;
    __syncthreads();
    float qa = bq[t];
    for (int i = 0; i < 64; ++i) qa = fmaf(sa[i], wq[i * 64 + t], qa);
    q_out[b * 64 + t] = qa;
}

// ---------------- attention: chunked online softmax partials ----------------
__global__ __launch_bounds__(256) void k_attn(const float* __restrict__ q,
                                              const float* __restrict__ kb,
                                              const float* __restrict__ vb,
                                              float* __restrict__ part) {
    int id = blockIdx.x;
    int ch = id % NCH;
    int bh = id / NCH;
    int b = bh / HEADS_, hd = bh % HEADS_;
    float qv[16];
#pragma unroll
    for (int d = 0; d < 16; ++d) qv[d] = q[b * 64 + hd * 16 + d];
    float m = -1e30f, s = 0.f, c[16];
#pragma unroll
    for (int d = 0; d < 16; ++d) c[d] = 0.f;
    int n0 = ch * CS;
    int n1 = n0 + CS; if (n1 > N_) n1 = N_;
    for (int n = n0 + threadIdx.x; n < n1; n += 256) {
        const float4* kr = (const float4*)(kb + ((size_t)b * N_ + n) * 64 + hd * 16);
        float kk[16];
        ((float4*)kk)[0] = kr[0]; ((float4*)kk)[1] = kr[1];
        ((float4*)kk)[2] = kr[2]; ((float4*)kk)[3] = kr[3];
        float dot = 0.f;
#pragma unroll
        for (int d = 0; d < 16; ++d) dot = fmaf(qv[d], kk[d], dot);
        dot *= 0.25f;
        float nm = fmaxf(m, dot);
        float p = __expf(dot - nm);
        float cor = __expf(m - nm);
        const float4* vr = (const float4*)(vb + ((size_t)b * N_ + n) * 64 + hd * 16);
        float vv[16];
        ((float4*)vv)[0] = vr[0]; ((float4*)vv)[1] = vr[1];
        ((float4*)vv)[2] = vr[2]; ((float4*)vv)[3] = vr[3];
        s = s * cor + p;
#pragma unroll
        for (int d = 0; d < 16; ++d) c[d] = c[d] * cor + p * vv[d];
        m = nm;
    }
#pragma unroll
    for (int o = 1; o < 64; o <<= 1) {
        float m2 = __shfl_xor(m, o);
        float s2 = __shfl_xor(s, o);
        float nm = fmaxf(m, m2);
        float w1 = __expf(m - nm), w2 = __expf(m2 - nm);
        s = s * w1 + s2 * w2;
#pragma unroll
        for (int d = 0; d < 16; ++d) {
            float c2 = __shfl_xor(c[d], o);
            c[d] = c[d] * w1 + c2 * w2;
        }
        m = nm;
    }
    __shared__ float red[4][18];
    int wv_ = threadIdx.x >> 6, lane = threadIdx.x & 63;
    if (lane == 0) {
        red[wv_][0] = m; red[wv_][1] = s;
#pragma unroll
        for (int d = 0; d < 16; ++d) red[wv_][2 + d] = c[d];
    }
    __syncthreads();
    if (threadIdx.x == 0) {
        float gm = red[0][0];
        for (int w = 1; w < 4; ++w) gm = fmaxf(gm, red[w][0]);
        float gs = 0.f, gc[16];
#pragma unroll
        for (int d = 0; d < 16; ++d) gc[d] = 0.f;
        for (int w = 0; w < 4; ++w) {
            float ww = __expf(red[w][0] - gm);
            gs += red[w][1] * ww;
#pragma unroll
            for (int d = 0; d < 16; ++d) gc[d] += red[w][2 + d] * ww;
        }
        float* p = part + (size_t)id * 18;
        p[0] = gm; p[1] = gs;
#pragma unroll
        for (int d = 0; d < 16; ++d) p[2 + d] = gc[d];
    }
}

__global__ __launch_bounds__(64) void k_comb(const float* __restrict__ part,
                                             float* __restrict__ ctx) {
    int bh = blockIdx.x, t = threadIdx.x;
    int b = bh / HEADS_, hd = bh % HEADS_;
    const float* p = part + ((size_t)bh * NCH + t) * 18;
    float m = p[0], s = p[1], c[16];
#pragma unroll
    for (int d = 0; d < 16; ++d) c[d] = p[2 + d];
    float gm = m;
#pragma unroll
    for (int o = 1; o < 64; o <<= 1) gm = fmaxf(gm, __shfl_xor(gm, o));
    float w = __expf(m - gm);
    float sw = s * w;
#pragma unroll
    for (int o = 1; o < 64; o <<= 1) sw += __shfl_xor(sw, o);
    float cg[16];
#pragma unroll
    for (int d = 0; d < 16; ++d) {
        float x = c[d] * w;
#pragma unroll
        for (int o = 1; o < 64; o <<= 1) x += __shfl_xor(x, o);
        cg[d] = x;
    }
    if (t == 0) {
#pragma unroll
        for (int d = 0; d < 16; ++d) ctx[b * 64 + hd * 16 + d] = cg[d] / sw;
    }
}

// ---------------- g = LN(a + ctx@wo + bo); wcomb = g/8 + policy_w ----------------
__global__ __launch_bounds__(64) void k_g(const float* __restrict__ a,
                                          const float* __restrict__ ctx,
                                          const float* __restrict__ wo,
                                          const float* __restrict__ bo,
                                          const float* __restrict__ lng,
                                          const float* __restrict__ lnb,
                                          const float* __restrict__ pw,
                                          float* __restrict__ wcomb) {
    int b = blockIdx.x, t = threadIdx.x;
    __shared__ float sc[64];
    sc[t] = ctx[b * 64 + t];
    __syncthreads();
    float o = bo[t];
    for (int i = 0; i < 64; ++i) o = fmaf(sc[i], wo[i * 64 + t], o);
    float y = a[b * 64 + t] + o;
    float mu = y;
#pragma unroll
    for (int oo = 1; oo < 64; oo <<= 1) mu += __shfl_xor(mu, oo);
    mu *= (1.f / 64.f);
    float d = y - mu;
    float var = d * d;
#pragma unroll
    for (int oo = 1; oo < 64; oo <<= 1) var += __shfl_xor(var, oo);
    var *= (1.f / 64.f);
    float g = d * rsqrtf(var + 1e-5f) * lng[t] + lnb[t];
    wcomb[b * 64 + t] = g * 0.125f + pw[t];
}

// ---------------- logits ----------------
__global__ __launch_bounds__(256) void k_final(const float* __restrict__ h,
                                               const float* __restrict__ wcomb,
                                               const float* __restrict__ pb,
                                               const void* __restrict__ mask,
                                               const int* __restrict__ flagp,
                                               float* __restrict__ out) {
    int idx = blockIdx.x * 256 + threadIdx.x;
    if (idx >= B_ * N_) return;
    int b = idx / N_;
    const float4* wr = (const float4*)(wcomb + b * 64);
    const float4* hr = (const float4*)(h + (size_t)idx * 64);
    float acc = pb[0];
#pragma unroll
    for (int i = 0; i < 16; ++i) {
        float4 hv = hr[i], wv = wr[i];
        acc = fmaf(hv.x, wv.x, acc);
        acc = fmaf(hv.y, wv.y, acc);
        acc = fmaf(hv.z, wv.z, acc);
        acc = fmaf(hv.w, wv.w, acc);
    }
    int flag = *flagp;
    bool mv;
    if (flag == 1)      mv = ((const int*)mask)[idx] != 0;
    else if (flag == 2) mv = ((const float*)mask)[idx] != 0.f;
    else                mv = ((const unsigned char*)mask)[idx] != 0;
    out[idx] = mv ? acc : -1.0e9f;
}

extern "C" void kernel_launch(void* const* d_in, const int* in_sizes, int n_in,
                              void* d_out, int out_size, void* d_ws, size_t ws_size,
                              hipStream_t stream) {
    const float* gn   = (const float*)d_in[0];
    const float* ad   = (const float*)d_in[1];
    const float* wnod = (const float*)d_in[2];
    const float* bnod = (const float*)d_in[3];
    const float* msgw = (const float*)d_in[4];
    const float* msgb = (const float*)d_in[5];
    const float* updw = (const float*)d_in[6];
    const float* updb = (const float*)d_in[7];
    const float* wad  = (const float*)d_in[8];
    const float* bad  = (const float*)d_in[9];
    const float* wq   = (const float*)d_in[10];
    const float* bq   = (const float*)d_in[11];
    const float* wk   = (const float*)d_in[12];
    const float* bk   = (const float*)d_in[13];
    const float* wv   = (const float*)d_in[14];
    const float* bv   = (const float*)d_in[15];
    const float* wo   = (const float*)d_in[16];
    const float* bo   = (const float*)d_in[17];
    const float* lng  = (const float*)d_in[18];
    const float* lnb  = (const float*)d_in[19];
    const float* pw   = (const float*)d_in[20];
    const float* pb   = (const float*)d_in[21];
    const int*   links= (const int*)d_in[22];
    const void*  mask = d_in[23];

    char* ws = (char*)d_ws;
    float* h    = (float*)(ws + OFF_H);
    float* bufA = (float*)(ws + OFF_A1);
    float* bufB = (float*)(ws + OFF_A2);
    int*   cnt  = (int*)(ws + OFF_CNT);
    int*   pos  = (int*)(ws + OFF_POS);
    int*   offs = (int*)(ws + OFF_OFFS);
    int*   esrc = (int*)(ws + OFF_ESRC);
    int*   edst = (int*)(ws + OFF_EDST);
    unsigned short* hb16 = (unsigned short*)(ws + OFF_HB16);
    float* avec = (float*)(ws + OFF_AVEC);
    float* qvec = (float*)(ws + OFF_Q);
    float* ctx  = (float*)(ws + OFF_CTX);
    float* wcmb = (float*)(ws + OFF_WCMB);
    int*   flag = (int*)(ws + OFF_FLAG);
    float* part = (float*)(ws + OFF_PART);
    float* out  = (float*)d_out;

    hipMemsetAsync(cnt, 0, (size_t)B_ * N_ * 4, stream);
    k_maskdetect<<<1, 1, 0, stream>>>((const unsigned int*)mask, flag);
    k_embed<<<4096, 256, 0, stream>>>(gn, wnod, bnod, h, hb16);
    int eb = (B_ * E_ + 255) / 256;
    k_count<<<eb, 256, 0, stream>>>(links, cnt);
    k_scan<<<B_, 1024, 0, stream>>>(cnt, offs, pos);
    k_fill<<<eb, 256, 0, stream>>>(links, pos, esrc, edst);

    for (int l = 0; l < 2; ++l) {
        const float* mwl = msgw + (size_t)l * 128 * 64;
        const float* mbl = msgb + (size_t)l * 64;
        const float* uwl = updw + (size_t)l * 128 * 64;
        const float* ubl = updb + (size_t)l * 64;
        k_tdst_mfma<<<512, 256, 0, stream>>>(hb16, mwl, mbl, bufA);
        k_edge_csr<<<NT_ / 4, 256, 0, stream>>>(hb16, bufA, offs, esrc, edst, mwl, bufB);
        k_upd_mfma<<<512, 256, 0, stream>>>(h, hb16, bufB, uwl, ubl);
    }

    k_aq<<<B_, 64, 0, stream>>>(ad, wad, bad, wq, bq, avec, qvec);
    k_kv_mfma<<<512, 256, 0, stream>>>(hb16, wk, bk, wv, bv, bufA, bufB);
    k_attn<<<B_ * HEADS_ * NCH, 256, 0, stream>>>(qvec, bufA, bufB, part);
    k_comb<<<B_ * HEADS_, 64, 0, stream>>>(part, ctx);
    k_g<<<B_, 64, 0, stream>>>(avec, ctx, wo, bo, lng, lnb, pw, wcmb);
    k_final<<<(B_ * N_ + 255) / 256, 256, 0, stream>>>(h, wcmb, pb, mask, flag, out);
}

// Round 5
// 482.686 us; speedup vs baseline: 1.6815x; 1.6815x over previous
//
#include <hip/hip_runtime.h>
#include <hip/hip_bf16.h>
#include <math.h>

// Problem constants
constexpr int B_ = 4;
constexpr int N_ = 20000;
constexpr int E_ = 320000;
constexpr int HEADS_ = 4;
constexpr int NCH = 64;                       // attention chunks per (b,head)
constexpr int CS = (N_ + NCH - 1) / NCH;      // 313
constexpr int NT_ = (B_ * N_) / 16;           // 5000 node tiles

typedef __attribute__((ext_vector_type(8))) short short8;   // 8 bf16
typedef __attribute__((ext_vector_type(4))) float f32x4;

// Workspace layout (bytes). ~84 MB.
constexpr size_t HB = (size_t)B_ * N_ * 64 * 4;      // 20,480,000
constexpr size_t OFF_H    = 0;
constexpr size_t OFF_A1   = HB;            // tdb (bf16), later k (f32)
constexpr size_t OFF_A2   = 2 * HB;        // agg, later v
constexpr size_t OFF_CNT  = 3 * HB;                          // B*N ints
constexpr size_t OFF_POS  = OFF_CNT + (size_t)B_ * N_ * 4;   // B*N ints
constexpr size_t OFF_OFFS = OFF_POS + (size_t)B_ * N_ * 4;   // B*(N+1) ints
constexpr size_t OFF_ESRC = OFF_OFFS + ((size_t)B_ * (N_ + 1) * 4 + 64); // B*E ints
constexpr size_t OFF_EDST = OFF_ESRC + (size_t)B_ * E_ * 4;  // B*E ints
constexpr size_t OFF_HB16 = OFF_EDST + (size_t)B_ * E_ * 4;  // B*N*64 bf16
constexpr size_t OFF_AVEC = OFF_HB16 + (size_t)B_ * N_ * 64 * 2;
constexpr size_t OFF_Q    = OFF_AVEC + 1024;
constexpr size_t OFF_CTX  = OFF_Q + 1024;
constexpr size_t OFF_WCMB = OFF_CTX + 1024;
constexpr size_t OFF_FLAG = OFF_WCMB + 1024;
constexpr size_t OFF_PART = OFF_FLAG + 64;                   // 1024*18 f partials

static __device__ __forceinline__ unsigned short f2bf(float f) {
    union { float f; unsigned u; } v; v.f = f;
    unsigned r = v.u + 0x7fffu + ((v.u >> 16) & 1u);
    return (unsigned short)(r >> 16);
}
static __device__ __forceinline__ float bf2f(unsigned short u) {
    union { unsigned u; float f; } v; v.u = (unsigned)u << 16;
    return v.f;
}

// ---------------- mask dtype detection ----------------
__global__ void k_maskdetect(const unsigned int* __restrict__ m, int* __restrict__ flag) {
    if (blockIdx.x == 0 && threadIdx.x == 0) {
        bool alli = true, allf = true;
        for (int i = 0; i < 256; ++i) {
            unsigned v = m[i];
            alli = alli && (v <= 1u);
            allf = allf && (v == 0u || v == 0x3f800000u);
        }
        *flag = alli ? 1 : (allf ? 2 : 0);
    }
}

// ---------------- h = relu(gn @ w_node + b_node); hb16 = bf16(h) ----------------
__global__ __launch_bounds__(256) void k_embed(const float* __restrict__ gn,
                                               const float* __restrict__ w,
                                               const float* __restrict__ bias,
                                               float* __restrict__ h,
                                               unsigned short* __restrict__ hb16) {
    int lane = threadIdx.x & 63;
    float wc[16];
#pragma unroll
    for (int i = 0; i < 16; ++i) wc[i] = w[i * 64 + lane];
    float bb = bias[lane];
    int gw = (blockIdx.x * blockDim.x + threadIdx.x) >> 6;
    int nw = (gridDim.x * blockDim.x) >> 6;
    for (int node = gw; node < B_ * N_; node += nw) {
        const float* r = gn + (size_t)node * 16;
        float a0 = 0.f, a1 = 0.f, a2 = 0.f, a3 = 0.f;
#pragma unroll
        for (int i = 0; i < 16; i += 4) {
            a0 = fmaf(r[i + 0], wc[i + 0], a0);
            a1 = fmaf(r[i + 1], wc[i + 1], a1);
            a2 = fmaf(r[i + 2], wc[i + 2], a2);
            a3 = fmaf(r[i + 3], wc[i + 3], a3);
        }
        float v = fmaxf(bb + ((a0 + a1) + (a2 + a3)), 0.f);
        h[(size_t)node * 64 + lane] = v;
        hb16[(size_t)node * 64 + lane] = f2bf(v);
    }
}

// ---------------- CSR build ----------------
__global__ void k_count(const int* __restrict__ links, int* __restrict__ cnt) {
    int i = blockIdx.x * blockDim.x + threadIdx.x;
    if (i >= B_ * E_) return;
    int b = i / E_, e = i - b * E_;
    int dst = links[(size_t)b * 2 * E_ + E_ + e];
    atomicAdd(&cnt[b * N_ + dst], 1);
}

// 1024-thread shuffle-based scan
__global__ __launch_bounds__(1024) void k_scan(const int* __restrict__ cnt,
                                               int* __restrict__ offs,
                                               int* __restrict__ pos) {
    __shared__ int wsum[16];
    __shared__ int sbase;
    int b = blockIdx.x, t = threadIdx.x;
    int lane = t & 63, wv = t >> 6;
    if (t == 0) { sbase = 0; offs[(size_t)b * (N_ + 1)] = 0; }
    __syncthreads();
    for (int base = 0; base < N_; base += 1024) {
        int idx = base + t;
        int c = (idx < N_) ? cnt[(size_t)b * N_ + idx] : 0;
        int x = c;
#pragma unroll
        for (int o = 1; o < 64; o <<= 1) {
            int y = __shfl_up(x, o);
            if (lane >= o) x += y;
        }
        if (lane == 63) wsum[wv] = x;
        __syncthreads();
        if (wv == 0) {
            int s = (lane < 16) ? wsum[lane] : 0;
#pragma unroll
            for (int o = 1; o < 16; o <<= 1) {
                int y = __shfl_up(s, o);
                if (lane >= o) s += y;
            }
            if (lane < 16) wsum[lane] = s;
        }
        __syncthreads();
        int wpre = (wv > 0) ? wsum[wv - 1] : 0;
        int incl = x + wpre + sbase;
        if (idx < N_) {
            offs[(size_t)b * (N_ + 1) + idx + 1] = incl;
            pos[(size_t)b * N_ + idx] = incl - c;
        }
        __syncthreads();
        if (t == 1023) sbase = incl;
        __syncthreads();
    }
}

__global__ void k_fill(const int* __restrict__ links, int* __restrict__ pos,
                       int* __restrict__ esrc, int* __restrict__ edst) {
    int i = blockIdx.x * blockDim.x + threadIdx.x;
    if (i >= B_ * E_) return;
    int b = i / E_, e = i - b * E_;
    int src = links[(size_t)b * 2 * E_ + e];
    int dst = links[(size_t)b * 2 * E_ + E_ + e];
    int slot = atomicAdd(&pos[b * N_ + dst], 1);
    esrc[(size_t)b * E_ + slot] = src;
    edst[(size_t)b * E_ + slot] = dst;
}

// ---------------- tdst = W2^T h + msg_b (MFMA node GEMM, bf16 out) ----------------
__global__ __launch_bounds__(256) void k_tdst_mfma(const unsigned short* __restrict__ hb16,
                                                   const float* __restrict__ mw,
                                                   const float* __restrict__ mb,
                                                   unsigned short* __restrict__ tdb) {
    int lane = threadIdx.x & 63;
    int g = lane >> 4, c = lane & 15;
    short8 bf[4][2];
#pragma unroll
    for (int nt = 0; nt < 4; ++nt)
#pragma unroll
        for (int ks = 0; ks < 2; ++ks)
#pragma unroll
            for (int j = 0; j < 8; ++j)
                bf[nt][ks][j] = (short)f2bf(mw[(64 + ks * 32 + g * 8 + j) * 64 + nt * 16 + c]);
    float mbv[4];
#pragma unroll
    for (int nt = 0; nt < 4; ++nt) mbv[nt] = mb[nt * 16 + c];

    int wid = blockIdx.x * 4 + (threadIdx.x >> 6);
    int nw = gridDim.x * 4;
    f32x4 zero = {0.f, 0.f, 0.f, 0.f};
    for (int t = wid; t < NT_; t += nw) {
        const unsigned short* ap = hb16 + ((size_t)t * 16 + c) * 64;
        short8 a0 = *(const short8*)(ap + g * 8);
        short8 a1 = *(const short8*)(ap + 32 + g * 8);
        f32x4 acc[4];
#pragma unroll
        for (int nt = 0; nt < 4; ++nt) {
            acc[nt] = __builtin_amdgcn_mfma_f32_16x16x32_bf16(a0, bf[nt][0], zero, 0, 0, 0);
            acc[nt] = __builtin_amdgcn_mfma_f32_16x16x32_bf16(a1, bf[nt][1], acc[nt], 0, 0, 0);
        }
#pragma unroll
        for (int r = 0; r < 4; ++r) {
            size_t row = (size_t)t * 16 + 4 * g + r;
#pragma unroll
            for (int nt = 0; nt < 4; ++nt)
                tdb[row * 64 + nt * 16 + c] = f2bf(acc[nt][r] + mbv[nt]);
        }
    }
}

// ---------------- fused MFMA edge kernel (XCD-pinned per batch) ----------------
// Block i -> XCD i%8 (round-robin, m09); batch b = (i%8)>>1 so each XCD's
// working set (hb16+tdb of ONE batch, ~5MB) is ~L2-resident.
__global__ __launch_bounds__(256) void k_edge_mfma(const unsigned short* __restrict__ hb16,
                                                   const unsigned short* __restrict__ tdb,
                                                   const int* __restrict__ esrc,
                                                   const int* __restrict__ edst,
                                                   const float* __restrict__ mw,
                                                   float* __restrict__ agg) {
    int lane = threadIdx.x & 63;
    int g = lane >> 4, c = lane & 15;
    short8 bf[4][2];
#pragma unroll
    for (int nt = 0; nt < 4; ++nt)
#pragma unroll
        for (int ks = 0; ks < 2; ++ks)
#pragma unroll
            for (int j = 0; j < 8; ++j)
                bf[nt][ks][j] = (short)f2bf(mw[(ks * 32 + g * 8 + j) * 64 + nt * 16 + c]);

    int i = blockIdx.x;                       // 0..4999
    int b = (i & 7) >> 1;                     // batch (XCD-pinned pair)
    int o = ((i >> 3) << 1) | (i & 1);        // per-batch block ordinal 0..1249
    int w = threadIdx.x >> 6;
    const int* ep = esrc + (size_t)b * E_;
    const int* dp = edst + (size_t)b * E_;
    const unsigned short* hbase = hb16 + (size_t)(b * N_) * 64;
    const unsigned short* tbase = tdb + (size_t)(b * N_) * 64;
    float* abase = agg + (size_t)(b * N_) * 64;

    f32x4 zero = {0.f, 0.f, 0.f, 0.f};
#pragma unroll
    for (int k = 0; k < 4; ++k) {
        int t0 = (o * 4 + w) + k * 5000;      // tile 0..19999 within batch
        int s0 = t0 * 16;
        int src = ep[s0 + c];
        int dval = dp[s0 + c];
        const unsigned short* hrow = hbase + (size_t)src * 64;
        short8 a0 = *(const short8*)(hrow + g * 8);
        short8 a1 = *(const short8*)(hrow + 32 + g * 8);

        f32x4 acc[4];
#pragma unroll
        for (int nt = 0; nt < 4; ++nt) {
            acc[nt] = __builtin_amdgcn_mfma_f32_16x16x32_bf16(a0, bf[nt][0], zero, 0, 0, 0);
            acc[nt] = __builtin_amdgcn_mfma_f32_16x16x32_bf16(a1, bf[nt][1], acc[nt], 0, 0, 0);
        }

        // epilogue: rows 4g+r; add tdst[dst] (bf16, L2-pinned), relu
        float val[4][4]; // [nt][r]
#pragma unroll
        for (int r = 0; r < 4; ++r) {
            int dsg = __shfl(dval, 4 * g + r);
            const unsigned short* trow = tbase + (size_t)dsg * 64;
#pragma unroll
            for (int nt = 0; nt < 4; ++nt)
                val[nt][r] = fmaxf(acc[nt][r] + bf2f(trow[nt * 16 + c]), 0.f);
        }

        // segmented reduce over sorted dst runs (uniform loop, shfl broadcasts)
        int ii = 0;
        while (ii < 16) {
            int d = __shfl(dval, ii);
            int j = ii + 1;
            while (j < 16 && __shfl(dval, j) == d) ++j;
            float s0v = 0.f, s1v = 0.f, s2v = 0.f, s3v = 0.f;
#pragma unroll
            for (int r = 0; r < 4; ++r) {
                int rr = 4 * g + r;
                bool in = (rr >= ii) && (rr < j);
                s0v += in ? val[0][r] : 0.f;
                s1v += in ? val[1][r] : 0.f;
                s2v += in ? val[2][r] : 0.f;
                s3v += in ? val[3][r] : 0.f;
            }
            s0v += __shfl_xor(s0v, 16); s0v += __shfl_xor(s0v, 32);
            s1v += __shfl_xor(s1v, 16); s1v += __shfl_xor(s1v, 32);
            s2v += __shfl_xor(s2v, 16); s2v += __shfl_xor(s2v, 32);
            s3v += __shfl_xor(s3v, 16); s3v += __shfl_xor(s3v, 32);
            float outv = (g == 0) ? s0v : (g == 1) ? s1v : (g == 2) ? s2v : s3v;
            atomicAdd(&abase[(size_t)d * 64 + lane], outv);
            ii = j;
        }
    }
}

// ---------------- h += relu([h,agg] @ upd_w + upd_b) (MFMA) ----------------
__global__ __launch_bounds__(256) void k_upd_mfma(float* __restrict__ h,
                                                  unsigned short* __restrict__ hb16,
                                                  const float* __restrict__ agg,
                                                  const float* __restrict__ uw,
                                                  const float* __restrict__ ub) {
    int lane = threadIdx.x & 63;
    int g = lane >> 4, c = lane & 15;
    short8 bh[4][2], ba[4][2];
#pragma unroll
    for (int nt = 0; nt < 4; ++nt)
#pragma unroll
        for (int ks = 0; ks < 2; ++ks)
#pragma unroll
            for (int j = 0; j < 8; ++j) {
                bh[nt][ks][j] = (short)f2bf(uw[(ks * 32 + g * 8 + j) * 64 + nt * 16 + c]);
                ba[nt][ks][j] = (short)f2bf(uw[(64 + ks * 32 + g * 8 + j) * 64 + nt * 16 + c]);
            }
    float ubv[4];
#pragma unroll
    for (int nt = 0; nt < 4; ++nt) ubv[nt] = ub[nt * 16 + c];

    int wid = blockIdx.x * 4 + (threadIdx.x >> 6);
    int nw = gridDim.x * 4;
    f32x4 zero = {0.f, 0.f, 0.f, 0.f};
    for (int t = wid; t < NT_; t += nw) {
        const unsigned short* ap = hb16 + ((size_t)t * 16 + c) * 64;
        short8 a0 = *(const short8*)(ap + g * 8);
        short8 a1 = *(const short8*)(ap + 32 + g * 8);

        const float* gp = agg + ((size_t)t * 16 + c) * 64;
        float4 q0 = *(const float4*)(gp + g * 8);
        float4 q1 = *(const float4*)(gp + g * 8 + 4);
        float4 q2 = *(const float4*)(gp + 32 + g * 8);
        float4 q3 = *(const float4*)(gp + 32 + g * 8 + 4);
        short8 s0, s1;
        s0[0] = (short)f2bf(q0.x); s0[1] = (short)f2bf(q0.y);
        s0[2] = (short)f2bf(q0.z); s0[3] = (short)f2bf(q0.w);
        s0[4] = (short)f2bf(q1.x); s0[5] = (short)f2bf(q1.y);
        s0[6] = (short)f2bf(q1.z); s0[7] = (short)f2bf(q1.w);
        s1[0] = (short)f2bf(q2.x); s1[1] = (short)f2bf(q2.y);
        s1[2] = (short)f2bf(q2.z); s1[3] = (short)f2bf(q2.w);
        s1[4] = (short)f2bf(q3.x); s1[5] = (short)f2bf(q3.y);
        s1[6] = (short)f2bf(q3.z); s1[7] = (short)f2bf(q3.w);

        f32x4 acc[4];
#pragma unroll
        for (int nt = 0; nt < 4; ++nt) {
            acc[nt] = __builtin_amdgcn_mfma_f32_16x16x32_bf16(a0, bh[nt][0], zero, 0, 0, 0);
            acc[nt] = __builtin_amdgcn_mfma_f32_16x16x32_bf16(a1, bh[nt][1], acc[nt], 0, 0, 0);
            acc[nt] = __builtin_amdgcn_mfma_f32_16x16x32_bf16(s0, ba[nt][0], acc[nt], 0, 0, 0);
            acc[nt] = __builtin_amdgcn_mfma_f32_16x16x32_bf16(s1, ba[nt][1], acc[nt], 0, 0, 0);
        }
#pragma unroll
        for (int r = 0; r < 4; ++r) {
            size_t row = (size_t)t * 16 + 4 * g + r;
#pragma unroll
            for (int nt = 0; nt < 4; ++nt) {
                size_t idx = row * 64 + nt * 16 + c;
                float v = h[idx] + fmaxf(acc[nt][r] + ubv[nt], 0.f);
                h[idx] = v;
                hb16[idx] = f2bf(v);
            }
        }
    }
}

// ---------------- k/v projections (MFMA) ----------------
__global__ __launch_bounds__(256) void k_kv_mfma(const unsigned short* __restrict__ hb16,
                                                 const float* __restrict__ wk,
                                                 const float* __restrict__ bk,
                                                 const float* __restrict__ wv,
                                                 const float* __restrict__ bv,
                                                 float* __restrict__ kb,
                                                 float* __restrict__ vb) {
    int lane = threadIdx.x & 63;
    int g = lane >> 4, c = lane & 15;
    short8 bkf[4][2], bvf[4][2];
#pragma unroll
    for (int nt = 0; nt < 4; ++nt)
#pragma unroll
        for (int ks = 0; ks < 2; ++ks)
#pragma unroll
            for (int j = 0; j < 8; ++j) {
                bkf[nt][ks][j] = (short)f2bf(wk[(ks * 32 + g * 8 + j) * 64 + nt * 16 + c]);
                bvf[nt][ks][j] = (short)f2bf(wv[(ks * 32 + g * 8 + j) * 64 + nt * 16 + c]);
            }
    float bkv[4], bvv[4];
#pragma unroll
    for (int nt = 0; nt < 4; ++nt) { bkv[nt] = bk[nt * 16 + c]; bvv[nt] = bv[nt * 16 + c]; }

    int wid = blockIdx.x * 4 + (threadIdx.x >> 6);
    int nw = gridDim.x * 4;
    f32x4 zero = {0.f, 0.f, 0.f, 0.f};
    for (int t = wid; t < NT_; t += nw) {
        const unsigned short* ap = hb16 + ((size_t)t * 16 + c) * 64;
        short8 a0 = *(const short8*)(ap + g * 8);
        short8 a1 = *(const short8*)(ap + 32 + g * 8);
        f32x4 ak[4], av[4];
#pragma unroll
        for (int nt = 0; nt < 4; ++nt) {
            ak[nt] = __builtin_amdgcn_mfma_f32_16x16x32_bf16(a0, bkf[nt][0], zero, 0, 0, 0);
            ak[nt] = __builtin_amdgcn_mfma_f32_16x16x32_bf16(a1, bkf[nt][1], ak[nt], 0, 0, 0);
            av[nt] = __builtin_amdgcn_mfma_f32_16x16x32_bf16(a0, bvf[nt][0], zero, 0, 0, 0);
            av[nt] = __builtin_amdgcn_mfma_f32_16x16x32_bf16(a1, bvf[nt][1], av[nt], 0, 0, 0);
        }
#pragma unroll
        for (int r = 0; r < 4; ++r) {
            size_t row = (size_t)t * 16 + 4 * g + r;
#pragma unroll
            for (int nt = 0; nt < 4; ++nt) {
                kb[row * 64 + nt * 16 + c] = ak[nt][r] + bkv[nt];
                vb[row * 64 + nt * 16 + c] = av[nt][r] + bvv[nt];
            }
        }
    }
}

// ---------------- a = relu(ad @ w_ad + b_ad); q = a @ wq + bq ----------------
__global__ __launch_bounds__(64) void k_aq(const float* __restrict__ ad,
                                           const float* __restrict__ wad,
                                           const float* __restrict__ bad,
                                           const float* __restrict__ wq,
                                           const float* __restrict__ bq,
                                           float* __restrict__ a_out,
                                           float* __restrict__ q_out) {
    int b = blockIdx.x, t = threadIdx.x;
    __shared__ float sa[64];
    float acc = bad[t];
#pragma unroll
    for (int i = 0; i < 8; ++i) acc = fmaf(ad[b * 8 + i], wad[i * 64 + t], acc);
    float av = fmaxf(acc, 0.f);
    sa[t] = av;
    a_out[b * 64 + t] = av;
    __syncthreads();
    float qa = bq[t];
    for (int i = 0; i < 64; ++i) qa = fmaf(sa[i], wq[i * 64 + t], qa);
    q_out[b * 64 + t] = qa;
}

// ---------------- attention: chunked online softmax partials ----------------
__global__ __launch_bounds__(256) void k_attn(const float* __restrict__ q,
                                              const float* __restrict__ kb,
                                              const float* __restrict__ vb,
                                              float* __restrict__ part) {
    int id = blockIdx.x;
    int ch = id % NCH;
    int bh = id / NCH;
    int b = bh / HEADS_, hd = bh % HEADS_;
    float qv[16];
#pragma unroll
    for (int d = 0; d < 16; ++d) qv[d] = q[b * 64 + hd * 16 + d];
    float m = -1e30f, s = 0.f, c[16];
#pragma unroll
    for (int d = 0; d < 16; ++d) c[d] = 0.f;
    int n0 = ch * CS;
    int n1 = n0 + CS; if (n1 > N_) n1 = N_;
    for (int n = n0 + threadIdx.x; n < n1; n += 256) {
        const float4* kr = (const float4*)(kb + ((size_t)b * N_ + n) * 64 + hd * 16);
        float kk[16];
        ((float4*)kk)[0] = kr[0]; ((float4*)kk)[1] = kr[1];
        ((float4*)kk)[2] = kr[2]; ((float4*)kk)[3] = kr[3];
        float dot = 0.f;
#pragma unroll
        for (int d = 0; d < 16; ++d) dot = fmaf(qv[d], kk[d], dot);
        dot *= 0.25f;
        float nm = fmaxf(m, dot);
        float p = __expf(dot - nm);
        float cor = __expf(m - nm);
        const float4* vr = (const float4*)(vb + ((size_t)b * N_ + n) * 64 + hd * 16);
        float vv[16];
        ((float4*)vv)[0] = vr[0]; ((float4*)vv)[1] = vr[1];
        ((float4*)vv)[2] = vr[2]; ((float4*)vv)[3] = vr[3];
        s = s * cor + p;
#pragma unroll
        for (int d = 0; d < 16; ++d) c[d] = c[d] * cor + p * vv[d];
        m = nm;
    }
#pragma unroll
    for (int o = 1; o < 64; o <<= 1) {
        float m2 = __shfl_xor(m, o);
        float s2 = __shfl_xor(s, o);
        float nm = fmaxf(m, m2);
        float w1 = __expf(m - nm), w2 = __expf(m2 - nm);
        s = s * w1 + s2 * w2;
#pragma unroll
        for (int d = 0; d < 16; ++d) {
            float c2 = __shfl_xor(c[d], o);
            c[d] = c[d] * w1 + c2 * w2;
        }
        m = nm;
    }
    __shared__ float red[4][18];
    int wv_ = threadIdx.x >> 6, lane = threadIdx.x & 63;
    if (lane == 0) {
        red[wv_][0] = m; red[wv_][1] = s;
#pragma unroll
        for (int d = 0; d < 16; ++d) red[wv_][2 + d] = c[d];
    }
    __syncthreads();
    if (threadIdx.x == 0) {
        float gm = red[0][0];
        for (int w = 1; w < 4; ++w) gm = fmaxf(gm, red[w][0]);
        float gs = 0.f, gc[16];
#pragma unroll
        for (int d = 0; d < 16; ++d) gc[d] = 0.f;
        for (int w = 0; w < 4; ++w) {
            float ww = __expf(red[w][0] - gm);
            gs += red[w][1] * ww;
#pragma unroll
            for (int d = 0; d < 16; ++d) gc[d] += red[w][2 + d] * ww;
        }
        float* p = part + (size_t)id * 18;
        p[0] = gm; p[1] = gs;
#pragma unroll
        for (int d = 0; d < 16; ++d) p[2 + d] = gc[d];
    }
}

__global__ __launch_bounds__(64) void k_comb(const float* __restrict__ part,
                                             float* __restrict__ ctx) {
    int bh = blockIdx.x, t = threadIdx.x;
    int b = bh / HEADS_, hd = bh % HEADS_;
    const float* p = part + ((size_t)bh * NCH + t) * 18;
    float m = p[0], s = p[1], c[16];
#pragma unroll
    for (int d = 0; d < 16; ++d) c[d] = p[2 + d];
    float gm = m;
#pragma unroll
    for (int o = 1; o < 64; o <<= 1) gm = fmaxf(gm, __shfl_xor(gm, o));
    float w = __expf(m - gm);
    float sw = s * w;
#pragma unroll
    for (int o = 1; o < 64; o <<= 1) sw += __shfl_xor(sw, o);
    float cg[16];
#pragma unroll
    for (int d = 0; d < 16; ++d) {
        float x = c[d] * w;
#pragma unroll
        for (int o = 1; o < 64; o <<= 1) x += __shfl_xor(x, o);
        cg[d] = x;
    }
    if (t == 0) {
#pragma unroll
        for (int d = 0; d < 16; ++d) ctx[b * 64 + hd * 16 + d] = cg[d] / sw;
    }
}

// ---------------- g = LN(a + ctx@wo + bo); wcomb = g/8 + policy_w ----------------
__global__ __launch_bounds__(64) void k_g(const float* __restrict__ a,
                                          const float* __restrict__ ctx,
                                          const float* __restrict__ wo,
                                          const float* __restrict__ bo,
                                          const float* __restrict__ lng,
                                          const float* __restrict__ lnb,
                                          const float* __restrict__ pw,
                                          float* __restrict__ wcomb) {
    int b = blockIdx.x, t = threadIdx.x;
    __shared__ float sc[64];
    sc[t] = ctx[b * 64 + t];
    __syncthreads();
    float o = bo[t];
    for (int i = 0; i < 64; ++i) o = fmaf(sc[i], wo[i * 64 + t], o);
    float y = a[b * 64 + t] + o;
    float mu = y;
#pragma unroll
    for (int oo = 1; oo < 64; oo <<= 1) mu += __shfl_xor(mu, oo);
    mu *= (1.f / 64.f);
    float d = y - mu;
    float var = d * d;
#pragma unroll
    for (int oo = 1; oo < 64; oo <<= 1) var += __shfl_xor(var, oo);
    var *= (1.f / 64.f);
    float g = d * rsqrtf(var + 1e-5f) * lng[t] + lnb[t];
    wcomb[b * 64 + t] = g * 0.125f + pw[t];
}

// ---------------- logits ----------------
__global__ __launch_bounds__(256) void k_final(const float* __restrict__ h,
                                               const float* __restrict__ wcomb,
                                               const float* __restrict__ pb,
                                               const void* __restrict__ mask,
                                               const int* __restrict__ flagp,
                                               float* __restrict__ out) {
    int idx = blockIdx.x * 256 + threadIdx.x;
    if (idx >= B_ * N_) return;
    int b = idx / N_;
    const float4* wr = (const float4*)(wcomb + b * 64);
    const float4* hr = (const float4*)(h + (size_t)idx * 64);
    float acc = pb[0];
#pragma unroll
    for (int i = 0; i < 16; ++i) {
        float4 hv = hr[i], wv = wr[i];
        acc = fmaf(hv.x, wv.x, acc);
        acc = fmaf(hv.y, wv.y, acc);
        acc = fmaf(hv.z, wv.z, acc);
        acc = fmaf(hv.w, wv.w, acc);
    }
    int flag = *flagp;
    bool mv;
    if (flag == 1)      mv = ((const int*)mask)[idx] != 0;
    else if (flag == 2) mv = ((const float*)mask)[idx] != 0.f;
    else                mv = ((const unsigned char*)mask)[idx] != 0;
    out[idx] = mv ? acc : -1.0e9f;
}

extern "C" void kernel_launch(void* const* d_in, const int* in_sizes, int n_in,
                              void* d_out, int out_size, void* d_ws, size_t ws_size,
                              hipStream_t stream) {
    const float* gn   = (const float*)d_in[0];
    const float* ad   = (const float*)d_in[1];
    const float* wnod = (const float*)d_in[2];
    const float* bnod = (const float*)d_in[3];
    const float* msgw = (const float*)d_in[4];
    const float* msgb = (const float*)d_in[5];
    const float* updw = (const float*)d_in[6];
    const float* updb = (const float*)d_in[7];
    const float* wad  = (const float*)d_in[8];
    const float* bad  = (const float*)d_in[9];
    const float* wq   = (const float*)d_in[10];
    const float* bq   = (const float*)d_in[11];
    const float* wk   = (const float*)d_in[12];
    const float* bk   = (const float*)d_in[13];
    const float* wv   = (const float*)d_in[14];
    const float* bv   = (const float*)d_in[15];
    const float* wo   = (const float*)d_in[16];
    const float* bo   = (const float*)d_in[17];
    const float* lng  = (const float*)d_in[18];
    const float* lnb  = (const float*)d_in[19];
    const float* pw   = (const float*)d_in[20];
    const float* pb   = (const float*)d_in[21];
    const int*   links= (const int*)d_in[22];
    const void*  mask = d_in[23];

    char* ws = (char*)d_ws;
    float* h    = (float*)(ws + OFF_H);
    float* bufA = (float*)(ws + OFF_A1);
    unsigned short* tdb = (unsigned short*)(ws + OFF_A1);
    float* bufB = (float*)(ws + OFF_A2);
    int*   cnt  = (int*)(ws + OFF_CNT);
    int*   pos  = (int*)(ws + OFF_POS);
    int*   offs = (int*)(ws + OFF_OFFS);
    int*   esrc = (int*)(ws + OFF_ESRC);
    int*   edst = (int*)(ws + OFF_EDST);
    unsigned short* hb16 = (unsigned short*)(ws + OFF_HB16);
    float* avec = (float*)(ws + OFF_AVEC);
    float* qvec = (float*)(ws + OFF_Q);
    float* ctx  = (float*)(ws + OFF_CTX);
    float* wcmb = (float*)(ws + OFF_WCMB);
    int*   flag = (int*)(ws + OFF_FLAG);
    float* part = (float*)(ws + OFF_PART);
    float* out  = (float*)d_out;

    hipMemsetAsync(cnt, 0, (size_t)B_ * N_ * 4, stream);
    k_maskdetect<<<1, 1, 0, stream>>>((const unsigned int*)mask, flag);
    k_embed<<<4096, 256, 0, stream>>>(gn, wnod, bnod, h, hb16);
    int eb = (B_ * E_ + 255) / 256;
    k_count<<<eb, 256, 0, stream>>>(links, cnt);
    k_scan<<<B_, 1024, 0, stream>>>(cnt, offs, pos);
    k_fill<<<eb, 256, 0, stream>>>(links, pos, esrc, edst);

    for (int l = 0; l < 2; ++l) {
        const float* mwl = msgw + (size_t)l * 128 * 64;
        const float* mbl = msgb + (size_t)l * 64;
        const float* uwl = updw + (size_t)l * 128 * 64;
        const float* ubl = updb + (size_t)l * 64;
        k_tdst_mfma<<<512, 256, 0, stream>>>(hb16, mwl, mbl, tdb);
        hipMemsetAsync(bufB, 0, HB, stream);
        k_edge_mfma<<<5000, 256, 0, stream>>>(hb16, tdb, esrc, edst, mwl, bufB);
        k_upd_mfma<<<512, 256, 0, stream>>>(h, hb16, bufB, uwl, ubl);
    }

    k_aq<<<B_, 64, 0, stream>>>(ad, wad, bad, wq, bq, avec, qvec);
    k_kv_mfma<<<512, 256, 0, stream>>>(hb16, wk, bk, wv, bv, bufA, bufB);
    k_attn<<<B_ * HEADS_ * NCH, 256, 0, stream>>>(qvec, bufA, bufB, part);
    k_comb<<<B_ * HEADS_, 64, 0, stream>>>(part, ctx);
    k_g<<<B_, 64, 0, stream>>>(avec, ctx, wo, bo, lng, lnb, pw, wcmb);
    k_final<<<(B_ * N_ + 255) / 256, 256, 0, stream>>>(h, wcmb, pb, mask, flag, out);
}

// Round 6
// 465.725 us; speedup vs baseline: 1.7427x; 1.0364x over previous
//
#include <hip/hip_runtime.h>
#include <hip/hip_bf16.h>
#include <math.h>

// Problem constants
constexpr int B_ = 4;
constexpr int N_ = 20000;
constexpr int E_ = 320000;
constexpr int HEADS_ = 4;
constexpr int NCH = 64;                       // attention chunks per (b,head)
constexpr int CS = (N_ + NCH - 1) / NCH;      // 313
constexpr int NT_ = (B_ * N_) / 16;           // 5000 node tiles

typedef __attribute__((ext_vector_type(8))) short short8;   // 8 bf16
typedef __attribute__((ext_vector_type(4))) float f32x4;

// Workspace layout (bytes). ~84 MB.
constexpr size_t HB = (size_t)B_ * N_ * 64 * 4;      // 20,480,000
constexpr size_t OFF_H    = 0;
constexpr size_t OFF_A1   = HB;            // tdb (bf16), later k (f32)
constexpr size_t OFF_A2   = 2 * HB;        // agg, later v
constexpr size_t OFF_CNT  = 3 * HB;                          // B*N ints
constexpr size_t OFF_POS  = OFF_CNT + (size_t)B_ * N_ * 4;   // B*N ints
constexpr size_t OFF_OFFS = OFF_POS + (size_t)B_ * N_ * 4;   // B*(N+1) ints
constexpr size_t OFF_EPAIR= OFF_OFFS + ((size_t)B_ * (N_ + 1) * 4 + 64); // B*E int2
constexpr size_t OFF_HB16 = OFF_EPAIR + (size_t)B_ * E_ * 8; // B*N*64 bf16
constexpr size_t OFF_AVEC = OFF_HB16 + (size_t)B_ * N_ * 64 * 2;
constexpr size_t OFF_Q    = OFF_AVEC + 1024;
constexpr size_t OFF_CTX  = OFF_Q + 1024;
constexpr size_t OFF_WCMB = OFF_CTX + 1024;
constexpr size_t OFF_FLAG = OFF_WCMB + 1024;
constexpr size_t OFF_PART = OFF_FLAG + 64;                   // 1024*18 f partials

static __device__ __forceinline__ unsigned short f2bf(float f) {
    union { float f; unsigned u; } v; v.f = f;
    unsigned r = v.u + 0x7fffu + ((v.u >> 16) & 1u);
    return (unsigned short)(r >> 16);
}
static __device__ __forceinline__ float bf2f(unsigned short u) {
    union { unsigned u; float f; } v; v.u = (unsigned)u << 16;
    return v.f;
}

// ---------------- mask dtype detection ----------------
__global__ void k_maskdetect(const unsigned int* __restrict__ m, int* __restrict__ flag) {
    if (blockIdx.x == 0 && threadIdx.x == 0) {
        bool alli = true, allf = true;
        for (int i = 0; i < 256; ++i) {
            unsigned v = m[i];
            alli = alli && (v <= 1u);
            allf = allf && (v == 0u || v == 0x3f800000u);
        }
        *flag = alli ? 1 : (allf ? 2 : 0);
    }
}

// ---------------- h = relu(gn @ w_node + b_node); hb16 = bf16(h) ----------------
__global__ __launch_bounds__(256) void k_embed(const float* __restrict__ gn,
                                               const float* __restrict__ w,
                                               const float* __restrict__ bias,
                                               float* __restrict__ h,
                                               unsigned short* __restrict__ hb16) {
    int lane = threadIdx.x & 63;
    float wc[16];
#pragma unroll
    for (int i = 0; i < 16; ++i) wc[i] = w[i * 64 + lane];
    float bb = bias[lane];
    int gw = (blockIdx.x * blockDim.x + threadIdx.x) >> 6;
    int nw = (gridDim.x * blockDim.x) >> 6;
    for (int node = gw; node < B_ * N_; node += nw) {
        const float* r = gn + (size_t)node * 16;
        float a0 = 0.f, a1 = 0.f, a2 = 0.f, a3 = 0.f;
#pragma unroll
        for (int i = 0; i < 16; i += 4) {
            a0 = fmaf(r[i + 0], wc[i + 0], a0);
            a1 = fmaf(r[i + 1], wc[i + 1], a1);
            a2 = fmaf(r[i + 2], wc[i + 2], a2);
            a3 = fmaf(r[i + 3], wc[i + 3], a3);
        }
        float v = fmaxf(bb + ((a0 + a1) + (a2 + a3)), 0.f);
        h[(size_t)node * 64 + lane] = v;
        hb16[(size_t)node * 64 + lane] = f2bf(v);
    }
}

// ---------------- CSR build (XCD-pinned per batch) ----------------
// Block i -> XCD i%8; batch b = (i%8)>>1 so each batch's cnt/pos/epair region
// is touched by only 2 XCDs -> scatter lines coalesce in L2.
__global__ __launch_bounds__(256) void k_count(const int* __restrict__ links,
                                               int* __restrict__ cnt) {
    int i = blockIdx.x;                   // 0..4999
    int b = (i & 7) >> 1;
    int o = ((i >> 3) << 1) | (i & 1);    // 0..1249
    int e = o * 256 + threadIdx.x;
    int dst = links[(size_t)b * 2 * E_ + E_ + e];
    atomicAdd(&cnt[b * N_ + dst], 1);
}

// 1024-thread shuffle-based scan
__global__ __launch_bounds__(1024) void k_scan(const int* __restrict__ cnt,
                                               int* __restrict__ offs,
                                               int* __restrict__ pos) {
    __shared__ int wsum[16];
    __shared__ int sbase;
    int b = blockIdx.x, t = threadIdx.x;
    int lane = t & 63, wv = t >> 6;
    if (t == 0) { sbase = 0; offs[(size_t)b * (N_ + 1)] = 0; }
    __syncthreads();
    for (int base = 0; base < N_; base += 1024) {
        int idx = base + t;
        int c = (idx < N_) ? cnt[(size_t)b * N_ + idx] : 0;
        int x = c;
#pragma unroll
        for (int o = 1; o < 64; o <<= 1) {
            int y = __shfl_up(x, o);
            if (lane >= o) x += y;
        }
        if (lane == 63) wsum[wv] = x;
        __syncthreads();
        if (wv == 0) {
            int s = (lane < 16) ? wsum[lane] : 0;
#pragma unroll
            for (int o = 1; o < 16; o <<= 1) {
                int y = __shfl_up(s, o);
                if (lane >= o) s += y;
            }
            if (lane < 16) wsum[lane] = s;
        }
        __syncthreads();
        int wpre = (wv > 0) ? wsum[wv - 1] : 0;
        int incl = x + wpre + sbase;
        if (idx < N_) {
            offs[(size_t)b * (N_ + 1) + idx + 1] = incl;
            pos[(size_t)b * N_ + idx] = incl - c;
        }
        __syncthreads();
        if (t == 1023) sbase = incl;
        __syncthreads();
    }
}

__global__ __launch_bounds__(256) void k_fill(const int* __restrict__ links,
                                              int* __restrict__ pos,
                                              int2* __restrict__ epair) {
    int i = blockIdx.x;                   // 0..4999
    int b = (i & 7) >> 1;
    int o = ((i >> 3) << 1) | (i & 1);    // 0..1249
    int e = o * 256 + threadIdx.x;
    int src = links[(size_t)b * 2 * E_ + e];
    int dst = links[(size_t)b * 2 * E_ + E_ + e];
    int slot = atomicAdd(&pos[b * N_ + dst], 1);
    epair[(size_t)b * E_ + slot] = make_int2(src, dst);
}

// ---------------- tdst = W2^T h + msg_b (MFMA node GEMM, bf16 out) ----------------
__global__ __launch_bounds__(256) void k_tdst_mfma(const unsigned short* __restrict__ hb16,
                                                   const float* __restrict__ mw,
                                                   const float* __restrict__ mb,
                                                   unsigned short* __restrict__ tdb) {
    int lane = threadIdx.x & 63;
    int g = lane >> 4, c = lane & 15;
    short8 bf[4][2];
#pragma unroll
    for (int nt = 0; nt < 4; ++nt)
#pragma unroll
        for (int ks = 0; ks < 2; ++ks)
#pragma unroll
            for (int j = 0; j < 8; ++j)
                bf[nt][ks][j] = (short)f2bf(mw[(64 + ks * 32 + g * 8 + j) * 64 + nt * 16 + c]);
    float mbv[4];
#pragma unroll
    for (int nt = 0; nt < 4; ++nt) mbv[nt] = mb[nt * 16 + c];

    int wid = blockIdx.x * 4 + (threadIdx.x >> 6);
    int nw = gridDim.x * 4;
    f32x4 zero = {0.f, 0.f, 0.f, 0.f};
    for (int t = wid; t < NT_; t += nw) {
        const unsigned short* ap = hb16 + ((size_t)t * 16 + c) * 64;
        short8 a0 = *(const short8*)(ap + g * 8);
        short8 a1 = *(const short8*)(ap + 32 + g * 8);
        f32x4 acc[4];
#pragma unroll
        for (int nt = 0; nt < 4; ++nt) {
            acc[nt] = __builtin_amdgcn_mfma_f32_16x16x32_bf16(a0, bf[nt][0], zero, 0, 0, 0);
            acc[nt] = __builtin_amdgcn_mfma_f32_16x16x32_bf16(a1, bf[nt][1], acc[nt], 0, 0, 0);
        }
#pragma unroll
        for (int r = 0; r < 4; ++r) {
            size_t row = (size_t)t * 16 + 4 * g + r;
#pragma unroll
            for (int nt = 0; nt < 4; ++nt)
                tdb[row * 64 + nt * 16 + c] = f2bf(acc[nt][r] + mbv[nt]);
        }
    }
}

// ---------------- fused MFMA edge kernel (XCD-pinned per batch) ----------------
__global__ __launch_bounds__(256) void k_edge_mfma(const unsigned short* __restrict__ hb16,
                                                   const unsigned short* __restrict__ tdb,
                                                   const int2* __restrict__ epair,
                                                   const float* __restrict__ mw,
                                                   float* __restrict__ agg) {
    int lane = threadIdx.x & 63;
    int g = lane >> 4, c = lane & 15;
    short8 bf[4][2];
#pragma unroll
    for (int nt = 0; nt < 4; ++nt)
#pragma unroll
        for (int ks = 0; ks < 2; ++ks)
#pragma unroll
            for (int j = 0; j < 8; ++j)
                bf[nt][ks][j] = (short)f2bf(mw[(ks * 32 + g * 8 + j) * 64 + nt * 16 + c]);

    int i = blockIdx.x;                       // 0..4999
    int b = (i & 7) >> 1;                     // batch (XCD-pinned pair)
    int o = ((i >> 3) << 1) | (i & 1);        // per-batch block ordinal 0..1249
    int w = threadIdx.x >> 6;
    const int2* pp = epair + (size_t)b * E_;
    const unsigned short* hbase = hb16 + (size_t)(b * N_) * 64;
    const unsigned short* tbase = tdb + (size_t)(b * N_) * 64;
    float* abase = agg + (size_t)(b * N_) * 64;

    f32x4 zero = {0.f, 0.f, 0.f, 0.f};
#pragma unroll
    for (int k = 0; k < 4; ++k) {
        int t0 = (o * 4 + w) + k * 5000;      // tile 0..19999 within batch
        int s0 = t0 * 16;
        int2 pr = pp[s0 + c];
        int src = pr.x;
        int dval = pr.y;
        const unsigned short* hrow = hbase + (size_t)src * 64;
        short8 a0 = *(const short8*)(hrow + g * 8);
        short8 a1 = *(const short8*)(hrow + 32 + g * 8);

        f32x4 acc[4];
#pragma unroll
        for (int nt = 0; nt < 4; ++nt) {
            acc[nt] = __builtin_amdgcn_mfma_f32_16x16x32_bf16(a0, bf[nt][0], zero, 0, 0, 0);
            acc[nt] = __builtin_amdgcn_mfma_f32_16x16x32_bf16(a1, bf[nt][1], acc[nt], 0, 0, 0);
        }

        // epilogue: rows 4g+r; add tdst[dst] (bf16, L2-pinned), relu
        float val[4][4]; // [nt][r]
#pragma unroll
        for (int r = 0; r < 4; ++r) {
            int dsg = __shfl(dval, 4 * g + r);
            const unsigned short* trow = tbase + (size_t)dsg * 64;
#pragma unroll
            for (int nt = 0; nt < 4; ++nt)
                val[nt][r] = fmaxf(acc[nt][r] + bf2f(trow[nt * 16 + c]), 0.f);
        }

        // segmented reduce over sorted dst runs (uniform loop, shfl broadcasts)
        int ii = 0;
        while (ii < 16) {
            int d = __shfl(dval, ii);
            int j = ii + 1;
            while (j < 16 && __shfl(dval, j) == d) ++j;
            float s0v = 0.f, s1v = 0.f, s2v = 0.f, s3v = 0.f;
#pragma unroll
            for (int r = 0; r < 4; ++r) {
                int rr = 4 * g + r;
                bool in = (rr >= ii) && (rr < j);
                s0v += in ? val[0][r] : 0.f;
                s1v += in ? val[1][r] : 0.f;
                s2v += in ? val[2][r] : 0.f;
                s3v += in ? val[3][r] : 0.f;
            }
            s0v += __shfl_xor(s0v, 16); s0v += __shfl_xor(s0v, 32);
            s1v += __shfl_xor(s1v, 16); s1v += __shfl_xor(s1v, 32);
            s2v += __shfl_xor(s2v, 16); s2v += __shfl_xor(s2v, 32);
            s3v += __shfl_xor(s3v, 16); s3v += __shfl_xor(s3v, 32);
            float outv = (g == 0) ? s0v : (g == 1) ? s1v : (g == 2) ? s2v : s3v;
            atomicAdd(&abase[(size_t)d * 64 + lane], outv);
            ii = j;
        }
    }
}

// ---------------- h += relu([h,agg] @ upd_w + upd_b) (MFMA) ----------------
__global__ __launch_bounds__(256) void k_upd_mfma(float* __restrict__ h,
                                                  unsigned short* __restrict__ hb16,
                                                  const float* __restrict__ agg,
                                                  const float* __restrict__ uw,
                                                  const float* __restrict__ ub) {
    int lane = threadIdx.x & 63;
    int g = lane >> 4, c = lane & 15;
    short8 bh[4][2], ba[4][2];
#pragma unroll
    for (int nt = 0; nt < 4; ++nt)
#pragma unroll
        for (int ks = 0; ks < 2; ++ks)
#pragma unroll
            for (int j = 0; j < 8; ++j) {
                bh[nt][ks][j] = (short)f2bf(uw[(ks * 32 + g * 8 + j) * 64 + nt * 16 + c]);
                ba[nt][ks][j] = (short)f2bf(uw[(64 + ks * 32 + g * 8 + j) * 64 + nt * 16 + c]);
            }
    float ubv[4];
#pragma unroll
    for (int nt = 0; nt < 4; ++nt) ubv[nt] = ub[nt * 16 + c];

    int wid = blockIdx.x * 4 + (threadIdx.x >> 6);
    int nw = gridDim.x * 4;
    f32x4 zero = {0.f, 0.f, 0.f, 0.f};
    for (int t = wid; t < NT_; t += nw) {
        const unsigned short* ap = hb16 + ((size_t)t * 16 + c) * 64;
        short8 a0 = *(const short8*)(ap + g * 8);
        short8 a1 = *(const short8*)(ap + 32 + g * 8);

        const float* gp = agg + ((size_t)t * 16 + c) * 64;
        float4 q0 = *(const float4*)(gp + g * 8);
        float4 q1 = *(const float4*)(gp + g * 8 + 4);
        float4 q2 = *(const float4*)(gp + 32 + g * 8);
        float4 q3 = *(const float4*)(gp + 32 + g * 8 + 4);
        short8 s0, s1;
        s0[0] = (short)f2bf(q0.x); s0[1] = (short)f2bf(q0.y);
        s0[2] = (short)f2bf(q0.z); s0[3] = (short)f2bf(q0.w);
        s0[4] = (short)f2bf(q1.x); s0[5] = (short)f2bf(q1.y);
        s0[6] = (short)f2bf(q1.z); s0[7] = (short)f2bf(q1.w);
        s1[0] = (short)f2bf(q2.x); s1[1] = (short)f2bf(q2.y);
        s1[2] = (short)f2bf(q2.z); s1[3] = (short)f2bf(q2.w);
        s1[4] = (short)f2bf(q3.x); s1[5] = (short)f2bf(q3.y);
        s1[6] = (short)f2bf(q3.z); s1[7] = (short)f2bf(q3.w);

        f32x4 acc[4];
#pragma unroll
        for (int nt = 0; nt < 4; ++nt) {
            acc[nt] = __builtin_amdgcn_mfma_f32_16x16x32_bf16(a0, bh[nt][0], zero, 0, 0, 0);
            acc[nt] = __builtin_amdgcn_mfma_f32_16x16x32_bf16(a1, bh[nt][1], acc[nt], 0, 0, 0);
            acc[nt] = __builtin_amdgcn_mfma_f32_16x16x32_bf16(s0, ba[nt][0], acc[nt], 0, 0, 0);
            acc[nt] = __builtin_amdgcn_mfma_f32_16x16x32_bf16(s1, ba[nt][1], acc[nt], 0, 0, 0);
        }
#pragma unroll
        for (int r = 0; r < 4; ++r) {
            size_t row = (size_t)t * 16 + 4 * g + r;
#pragma unroll
            for (int nt = 0; nt < 4; ++nt) {
                size_t idx = row * 64 + nt * 16 + c;
                float v = h[idx] + fmaxf(acc[nt][r] + ubv[nt], 0.f);
                h[idx] = v;
                hb16[idx] = f2bf(v);
            }
        }
    }
}

// ---------------- k/v projections (MFMA) ----------------
__global__ __launch_bounds__(256) void k_kv_mfma(const unsigned short* __restrict__ hb16,
                                                 const float* __restrict__ wk,
                                                 const float* __restrict__ bk,
                                                 const float* __restrict__ wv,
                                                 const float* __restrict__ bv,
                                                 float* __restrict__ kb,
                                                 float* __restrict__ vb) {
    int lane = threadIdx.x & 63;
    int g = lane >> 4, c = lane & 15;
    short8 bkf[4][2], bvf[4][2];
#pragma unroll
    for (int nt = 0; nt < 4; ++nt)
#pragma unroll
        for (int ks = 0; ks < 2; ++ks)
#pragma unroll
            for (int j = 0; j < 8; ++j) {
                bkf[nt][ks][j] = (short)f2bf(wk[(ks * 32 + g * 8 + j) * 64 + nt * 16 + c]);
                bvf[nt][ks][j] = (short)f2bf(wv[(ks * 32 + g * 8 + j) * 64 + nt * 16 + c]);
            }
    float bkv[4], bvv[4];
#pragma unroll
    for (int nt = 0; nt < 4; ++nt) { bkv[nt] = bk[nt * 16 + c]; bvv[nt] = bv[nt * 16 + c]; }

    int wid = blockIdx.x * 4 + (threadIdx.x >> 6);
    int nw = gridDim.x * 4;
    f32x4 zero = {0.f, 0.f, 0.f, 0.f};
    for (int t = wid; t < NT_; t += nw) {
        const unsigned short* ap = hb16 + ((size_t)t * 16 + c) * 64;
        short8 a0 = *(const short8*)(ap + g * 8);
        short8 a1 = *(const short8*)(ap + 32 + g * 8);
        f32x4 ak[4], av[4];
#pragma unroll
        for (int nt = 0; nt < 4; ++nt) {
            ak[nt] = __builtin_amdgcn_mfma_f32_16x16x32_bf16(a0, bkf[nt][0], zero, 0, 0, 0);
            ak[nt] = __builtin_amdgcn_mfma_f32_16x16x32_bf16(a1, bkf[nt][1], ak[nt], 0, 0, 0);
            av[nt] = __builtin_amdgcn_mfma_f32_16x16x32_bf16(a0, bvf[nt][0], zero, 0, 0, 0);
            av[nt] = __builtin_amdgcn_mfma_f32_16x16x32_bf16(a1, bvf[nt][1], av[nt], 0, 0, 0);
        }
#pragma unroll
        for (int r = 0; r < 4; ++r) {
            size_t row = (size_t)t * 16 + 4 * g + r;
#pragma unroll
            for (int nt = 0; nt < 4; ++nt) {
                kb[row * 64 + nt * 16 + c] = ak[nt][r] + bkv[nt];
                vb[row * 64 + nt * 16 + c] = av[nt][r] + bvv[nt];
            }
        }
    }
}

// ---------------- a = relu(ad @ w_ad + b_ad); q = a @ wq + bq ----------------
__global__ __launch_bounds__(64) void k_aq(const float* __restrict__ ad,
                                           const float* __restrict__ wad,
                                           const float* __restrict__ bad,
                                           const float* __restrict__ wq,
                                           const float* __restrict__ bq,
                                           float* __restrict__ a_out,
                                           float* __restrict__ q_out) {
    int b = blockIdx.x, t = threadIdx.x;
    __shared__ float sa[64];
    float acc = bad[t];
#pragma unroll
    for (int i = 0; i < 8; ++i) acc = fmaf(ad[b * 8 + i], wad[i * 64 + t], acc);
    float av = fmaxf(acc, 0.f);
    sa[t] = av;
    a_out[b * 64 + t] = av;
    __syncthreads();
    float qa = bq[t];
    for (int i = 0; i < 64; ++i) qa = fmaf(sa[i], wq[i * 64 + t], qa);
    q_out[b * 64 + t] = qa;
}

// ---------------- attention: chunked online softmax partials ----------------
__global__ __launch_bounds__(256) void k_attn(const float* __restrict__ q,
                                              const float* __restrict__ kb,
                                              const float* __restrict__ vb,
                                              float* __restrict__ part) {
    int id = blockIdx.x;
    int ch = id % NCH;
    int bh = id / NCH;
    int b = bh / HEADS_, hd = bh % HEADS_;
    float qv[16];
#pragma unroll
    for (int d = 0; d < 16; ++d) qv[d] = q[b * 64 + hd * 16 + d];
    float m = -1e30f, s = 0.f, c[16];
#pragma unroll
    for (int d = 0; d < 16; ++d) c[d] = 0.f;
    int n0 = ch * CS;
    int n1 = n0 + CS; if (n1 > N_) n1 = N_;
    for (int n = n0 + threadIdx.x; n < n1; n += 256) {
        const float4* kr = (const float4*)(kb + ((size_t)b * N_ + n) * 64 + hd * 16);
        float kk[16];
        ((float4*)kk)[0] = kr[0]; ((float4*)kk)[1] = kr[1];
        ((float4*)kk)[2] = kr[2]; ((float4*)kk)[3] = kr[3];
        float dot = 0.f;
#pragma unroll
        for (int d = 0; d < 16; ++d) dot = fmaf(qv[d], kk[d], dot);
        dot *= 0.25f;
        float nm = fmaxf(m, dot);
        float p = __expf(dot - nm);
        float cor = __expf(m - nm);
        const float4* vr = (const float4*)(vb + ((size_t)b * N_ + n) * 64 + hd * 16);
        float vv[16];
        ((float4*)vv)[0] = vr[0]; ((float4*)vv)[1] = vr[1];
        ((float4*)vv)[2] = vr[2]; ((float4*)vv)[3] = vr[3];
        s = s * cor + p;
#pragma unroll
        for (int d = 0; d < 16; ++d) c[d] = c[d] * cor + p * vv[d];
        m = nm;
    }
#pragma unroll
    for (int o = 1; o < 64; o <<= 1) {
        float m2 = __shfl_xor(m, o);
        float s2 = __shfl_xor(s, o);
        float nm = fmaxf(m, m2);
        float w1 = __expf(m - nm), w2 = __expf(m2 - nm);
        s = s * w1 + s2 * w2;
#pragma unroll
        for (int d = 0; d < 16; ++d) {
            float c2 = __shfl_xor(c[d], o);
            c[d] = c[d] * w1 + c2 * w2;
        }
        m = nm;
    }
    __shared__ float red[4][18];
    int wv_ = threadIdx.x >> 6, lane = threadIdx.x & 63;
    if (lane == 0) {
        red[wv_][0] = m; red[wv_][1] = s;
#pragma unroll
        for (int d = 0; d < 16; ++d) red[wv_][2 + d] = c[d];
    }
    __syncthreads();
    if (threadIdx.x == 0) {
        float gm = red[0][0];
        for (int w = 1; w < 4; ++w) gm = fmaxf(gm, red[w][0]);
        float gs = 0.f, gc[16];
#pragma unroll
        for (int d = 0; d < 16; ++d) gc[d] = 0.f;
        for (int w = 0; w < 4; ++w) {
            float ww = __expf(red[w][0] - gm);
            gs += red[w][1] * ww;
#pragma unroll
            for (int d = 0; d < 16; ++d) gc[d] += red[w][2 + d] * ww;
        }
        float* p = part + (size_t)id * 18;
        p[0] = gm; p[1] = gs;
#pragma unroll
        for (int d = 0; d < 16; ++d) p[2 + d] = gc[d];
    }
}

__global__ __launch_bounds__(64) void k_comb(const float* __restrict__ part,
                                             float* __restrict__ ctx) {
    int bh = blockIdx.x, t = threadIdx.x;
    int b = bh / HEADS_, hd = bh % HEADS_;
    const float* p = part + ((size_t)bh * NCH + t) * 18;
    float m = p[0], s = p[1], c[16];
#pragma unroll
    for (int d = 0; d < 16; ++d) c[d] = p[2 + d];
    float gm = m;
#pragma unroll
    for (int o = 1; o < 64; o <<= 1) gm = fmaxf(gm, __shfl_xor(gm, o));
    float w = __expf(m - gm);
    float sw = s * w;
#pragma unroll
    for (int o = 1; o < 64; o <<= 1) sw += __shfl_xor(sw, o);
    float cg[16];
#pragma unroll
    for (int d = 0; d < 16; ++d) {
        float x = c[d] * w;
#pragma unroll
        for (int o = 1; o < 64; o <<= 1) x += __shfl_xor(x, o);
        cg[d] = x;
    }
    if (t == 0) {
#pragma unroll
        for (int d = 0; d < 16; ++d) ctx[b * 64 + hd * 16 + d] = cg[d] / sw;
    }
}

// ---------------- g = LN(a + ctx@wo + bo); wcomb = g/8 + policy_w ----------------
__global__ __launch_bounds__(64) void k_g(const float* __restrict__ a,
                                          const float* __restrict__ ctx,
                                          const float* __restrict__ wo,
                                          const float* __restrict__ bo,
                                          const float* __restrict__ lng,
                                          const float* __restrict__ lnb,
                                          const float* __restrict__ pw,
                                          float* __restrict__ wcomb) {
    int b = blockIdx.x, t = threadIdx.x;
    __shared__ float sc[64];
    sc[t] = ctx[b * 64 + t];
    __syncthreads();
    float o = bo[t];
    for (int i = 0; i < 64; ++i) o = fmaf(sc[i], wo[i * 64 + t], o);
    float y = a[b * 64 + t] + o;
    float mu = y;
#pragma unroll
    for (int oo = 1; oo < 64; oo <<= 1) mu += __shfl_xor(mu, oo);
    mu *= (1.f / 64.f);
    float d = y - mu;
    float var = d * d;
#pragma unroll
    for (int oo = 1; oo < 64; oo <<= 1) var += __shfl_xor(var, oo);
    var *= (1.f / 64.f);
    float g = d * rsqrtf(var + 1e-5f) * lng[t] + lnb[t];
    wcomb[b * 64 + t] = g * 0.125f + pw[t];
}

// ---------------- logits ----------------
__global__ __launch_bounds__(256) void k_final(const float* __restrict__ h,
                                               const float* __restrict__ wcomb,
                                               const float* __restrict__ pb,
                                               const void* __restrict__ mask,
                                               const int* __restrict__ flagp,
                                               float* __restrict__ out) {
    int idx = blockIdx.x * 256 + threadIdx.x;
    if (idx >= B_ * N_) return;
    int b = idx / N_;
    const float4* wr = (const float4*)(wcomb + b * 64);
    const float4* hr = (const float4*)(h + (size_t)idx * 64);
    float acc = pb[0];
#pragma unroll
    for (int i = 0; i < 16; ++i) {
        float4 hv = hr[i], wv = wr[i];
        acc = fmaf(hv.x, wv.x, acc);
        acc = fmaf(hv.y, wv.y, acc);
        acc = fmaf(hv.z, wv.z, acc);
        acc = fmaf(hv.w, wv.w, acc);
    }
    int flag = *flagp;
    bool mv;
    if (flag == 1)      mv = ((const int*)mask)[idx] != 0;
    else if (flag == 2) mv = ((const float*)mask)[idx] != 0.f;
    else                mv = ((const unsigned char*)mask)[idx] != 0;
    out[idx] = mv ? acc : -1.0e9f;
}

extern "C" void kernel_launch(void* const* d_in, const int* in_sizes, int n_in,
                              void* d_out, int out_size, void* d_ws, size_t ws_size,
                              hipStream_t stream) {
    const float* gn   = (const float*)d_in[0];
    const float* ad   = (const float*)d_in[1];
    const float* wnod = (const float*)d_in[2];
    const float* bnod = (const float*)d_in[3];
    const float* msgw = (const float*)d_in[4];
    const float* msgb = (const float*)d_in[5];
    const float* updw = (const float*)d_in[6];
    const float* updb = (const float*)d_in[7];
    const float* wad  = (const float*)d_in[8];
    const float* bad  = (const float*)d_in[9];
    const float* wq   = (const float*)d_in[10];
    const float* bq   = (const float*)d_in[11];
    const float* wk   = (const float*)d_in[12];
    const float* bk   = (const float*)d_in[13];
    const float* wv   = (const float*)d_in[14];
    const float* bv   = (const float*)d_in[15];
    const float* wo   = (const float*)d_in[16];
    const float* bo   = (const float*)d_in[17];
    const float* lng  = (const float*)d_in[18];
    const float* lnb  = (const float*)d_in[19];
    const float* pw   = (const float*)d_in[20];
    const float* pb   = (const float*)d_in[21];
    const int*   links= (const int*)d_in[22];
    const void*  mask = d_in[23];

    char* ws = (char*)d_ws;
    float* h    = (float*)(ws + OFF_H);
    float* bufA = (float*)(ws + OFF_A1);
    unsigned short* tdb = (unsigned short*)(ws + OFF_A1);
    float* bufB = (float*)(ws + OFF_A2);
    int*   cnt  = (int*)(ws + OFF_CNT);
    int*   pos  = (int*)(ws + OFF_POS);
    int*   offs = (int*)(ws + OFF_OFFS);
    int2*  epair= (int2*)(ws + OFF_EPAIR);
    unsigned short* hb16 = (unsigned short*)(ws + OFF_HB16);
    float* avec = (float*)(ws + OFF_AVEC);
    float* qvec = (float*)(ws + OFF_Q);
    float* ctx  = (float*)(ws + OFF_CTX);
    float* wcmb = (float*)(ws + OFF_WCMB);
    int*   flag = (int*)(ws + OFF_FLAG);
    float* part = (float*)(ws + OFF_PART);
    float* out  = (float*)d_out;

    hipMemsetAsync(cnt, 0, (size_t)B_ * N_ * 4, stream);
    k_maskdetect<<<1, 1, 0, stream>>>((const unsigned int*)mask, flag);
    k_embed<<<4096, 256, 0, stream>>>(gn, wnod, bnod, h, hb16);
    k_count<<<5000, 256, 0, stream>>>(links, cnt);
    k_scan<<<B_, 1024, 0, stream>>>(cnt, offs, pos);
    k_fill<<<5000, 256, 0, stream>>>(links, pos, epair);

    for (int l = 0; l < 2; ++l) {
        const float* mwl = msgw + (size_t)l * 128 * 64;
        const float* mbl = msgb + (size_t)l * 64;
        const float* uwl = updw + (size_t)l * 128 * 64;
        const float* ubl = updb + (size_t)l * 64;
        k_tdst_mfma<<<512, 256, 0, stream>>>(hb16, mwl, mbl, tdb);
        hipMemsetAsync(bufB, 0, HB, stream);
        k_edge_mfma<<<5000, 256, 0, stream>>>(hb16, tdb, epair, mwl, bufB);
        k_upd_mfma<<<512, 256, 0, stream>>>(h, hb16, bufB, uwl, ubl);
    }

    k_aq<<<B_, 64, 0, stream>>>(ad, wad, bad, wq, bq, avec, qvec);
    k_kv_mfma<<<512, 256, 0, stream>>>(hb16, wk, bk, wv, bv, bufA, bufB);
    k_attn<<<B_ * HEADS_ * NCH, 256, 0, stream>>>(qvec, bufA, bufB, part);
    k_comb<<<B_ * HEADS_, 64, 0, stream>>>(part, ctx);
    k_g<<<B_, 64, 0, stream>>>(avec, ctx, wo, bo, lng, lnb, pw, wcmb);
    k_final<<<(B_ * N_ + 255) / 256, 256, 0, stream>>>(h, wcmb, pb, mask, flag, out);
}

// Round 7
// 407.862 us; speedup vs baseline: 1.9900x; 1.1419x over previous
//
#include <hip/hip_runtime.h>
#include <hip/hip_bf16.h>
#include <math.h>

// Problem constants
constexpr int B_ = 4;
constexpr int N_ = 20000;
constexpr int E_ = 320000;
constexpr int HEADS_ = 4;
constexpr int NCH = 64;                       // attention chunks per (b,head)
constexpr int CS = (N_ + NCH - 1) / NCH;      // 313
constexpr int NT_ = (B_ * N_) / 16;           // 5000 node tiles

typedef __attribute__((ext_vector_type(8))) short short8;   // 8 bf16
typedef __attribute__((ext_vector_type(4))) float f32x4;

// Workspace layout (bytes). ~84 MB (layout kept from R6).
constexpr size_t HB = (size_t)B_ * N_ * 64 * 4;      // 20,480,000
constexpr size_t OFF_H    = 0;             // (unused now)
constexpr size_t OFF_A1   = HB;            // tdb (bf16), later kb16
constexpr size_t OFF_A2   = 2 * HB;        // agg (f32), later vb16
constexpr size_t OFF_CNT  = 3 * HB;                          // B*N ints
constexpr size_t OFF_POS  = OFF_CNT + (size_t)B_ * N_ * 4;   // B*N ints
constexpr size_t OFF_OFFS = OFF_POS + (size_t)B_ * N_ * 4;   // B*(N+1) ints
constexpr size_t OFF_EPAIR= OFF_OFFS + ((size_t)B_ * (N_ + 1) * 4 + 64); // B*E int2
constexpr size_t OFF_HB16 = OFF_EPAIR + (size_t)B_ * E_ * 8; // B*N*64 bf16
constexpr size_t OFF_AVEC = OFF_HB16 + (size_t)B_ * N_ * 64 * 2;
constexpr size_t OFF_Q    = OFF_AVEC + 1024;
constexpr size_t OFF_CTX  = OFF_Q + 1024;
constexpr size_t OFF_WCMB = OFF_CTX + 1024;
constexpr size_t OFF_FLAG = OFF_WCMB + 1024;
constexpr size_t OFF_PART = OFF_FLAG + 64;                   // 1024*18 f partials

static __device__ __forceinline__ unsigned short f2bf(float f) {
    union { float f; unsigned u; } v; v.f = f;
    unsigned r = v.u + 0x7fffu + ((v.u >> 16) & 1u);
    return (unsigned short)(r >> 16);
}
static __device__ __forceinline__ float bf2f(unsigned short u) {
    union { unsigned u; float f; } v; v.u = (unsigned)u << 16;
    return v.f;
}

// ---------------- mask dtype detection ----------------
__global__ void k_maskdetect(const unsigned int* __restrict__ m, int* __restrict__ flag) {
    if (blockIdx.x == 0 && threadIdx.x == 0) {
        bool alli = true, allf = true;
        for (int i = 0; i < 256; ++i) {
            unsigned v = m[i];
            alli = alli && (v <= 1u);
            allf = allf && (v == 0u || v == 0x3f800000u);
        }
        *flag = alli ? 1 : (allf ? 2 : 0);
    }
}

// ---------------- hb16 = bf16(relu(gn @ w_node + b_node)) ----------------
__global__ __launch_bounds__(256) void k_embed(const float* __restrict__ gn,
                                               const float* __restrict__ w,
                                               const float* __restrict__ bias,
                                               unsigned short* __restrict__ hb16) {
    int lane = threadIdx.x & 63;
    float wc[16];
#pragma unroll
    for (int i = 0; i < 16; ++i) wc[i] = w[i * 64 + lane];
    float bb = bias[lane];
    int gw = (blockIdx.x * blockDim.x + threadIdx.x) >> 6;
    int nw = (gridDim.x * blockDim.x) >> 6;
    for (int node = gw; node < B_ * N_; node += nw) {
        const float* r = gn + (size_t)node * 16;
        float a0 = 0.f, a1 = 0.f, a2 = 0.f, a3 = 0.f;
#pragma unroll
        for (int i = 0; i < 16; i += 4) {
            a0 = fmaf(r[i + 0], wc[i + 0], a0);
            a1 = fmaf(r[i + 1], wc[i + 1], a1);
            a2 = fmaf(r[i + 2], wc[i + 2], a2);
            a3 = fmaf(r[i + 3], wc[i + 3], a3);
        }
        float v = fmaxf(bb + ((a0 + a1) + (a2 + a3)), 0.f);
        hb16[(size_t)node * 64 + lane] = f2bf(v);
    }
}

// ---------------- CSR build (XCD-pinned per batch) ----------------
__global__ __launch_bounds__(256) void k_count(const int* __restrict__ links,
                                               int* __restrict__ cnt) {
    int i = blockIdx.x;                   // 0..4999
    int b = (i & 7) >> 1;
    int o = ((i >> 3) << 1) | (i & 1);    // 0..1249
    int e = o * 256 + threadIdx.x;
    int dst = links[(size_t)b * 2 * E_ + E_ + e];
    atomicAdd(&cnt[b * N_ + dst], 1);
}

// 1024-thread shuffle-based scan
__global__ __launch_bounds__(1024) void k_scan(const int* __restrict__ cnt,
                                               int* __restrict__ offs,
                                               int* __restrict__ pos) {
    __shared__ int wsum[16];
    __shared__ int sbase;
    int b = blockIdx.x, t = threadIdx.x;
    int lane = t & 63, wv = t >> 6;
    if (t == 0) { sbase = 0; offs[(size_t)b * (N_ + 1)] = 0; }
    __syncthreads();
    for (int base = 0; base < N_; base += 1024) {
        int idx = base + t;
        int c = (idx < N_) ? cnt[(size_t)b * N_ + idx] : 0;
        int x = c;
#pragma unroll
        for (int o = 1; o < 64; o <<= 1) {
            int y = __shfl_up(x, o);
            if (lane >= o) x += y;
        }
        if (lane == 63) wsum[wv] = x;
        __syncthreads();
        if (wv == 0) {
            int s = (lane < 16) ? wsum[lane] : 0;
#pragma unroll
            for (int o = 1; o < 16; o <<= 1) {
                int y = __shfl_up(s, o);
                if (lane >= o) s += y;
            }
            if (lane < 16) wsum[lane] = s;
        }
        __syncthreads();
        int wpre = (wv > 0) ? wsum[wv - 1] : 0;
        int incl = x + wpre + sbase;
        if (idx < N_) {
            offs[(size_t)b * (N_ + 1) + idx + 1] = incl;
            pos[(size_t)b * N_ + idx] = incl - c;
        }
        __syncthreads();
        if (t == 1023) sbase = incl;
        __syncthreads();
    }
}

__global__ __launch_bounds__(256) void k_fill(const int* __restrict__ links,
                                              int* __restrict__ pos,
                                              int2* __restrict__ epair) {
    int i = blockIdx.x;                   // 0..4999
    int b = (i & 7) >> 1;
    int o = ((i >> 3) << 1) | (i & 1);    // 0..1249
    int e = o * 256 + threadIdx.x;
    int src = links[(size_t)b * 2 * E_ + e];
    int dst = links[(size_t)b * 2 * E_ + E_ + e];
    int slot = atomicAdd(&pos[b * N_ + dst], 1);
    epair[(size_t)b * E_ + slot] = make_int2(src, dst);
}

// ---------------- tdst = W2^T h + msg_b (MFMA node GEMM, bf16 out) ----------------
__global__ __launch_bounds__(256) void k_tdst_mfma(const unsigned short* __restrict__ hb16,
                                                   const float* __restrict__ mw,
                                                   const float* __restrict__ mb,
                                                   unsigned short* __restrict__ tdb) {
    int lane = threadIdx.x & 63;
    int g = lane >> 4, c = lane & 15;
    short8 bf[4][2];
#pragma unroll
    for (int nt = 0; nt < 4; ++nt)
#pragma unroll
        for (int ks = 0; ks < 2; ++ks)
#pragma unroll
            for (int j = 0; j < 8; ++j)
                bf[nt][ks][j] = (short)f2bf(mw[(64 + ks * 32 + g * 8 + j) * 64 + nt * 16 + c]);
    float mbv[4];
#pragma unroll
    for (int nt = 0; nt < 4; ++nt) mbv[nt] = mb[nt * 16 + c];

    int wid = blockIdx.x * 4 + (threadIdx.x >> 6);
    int nw = gridDim.x * 4;
    f32x4 zero = {0.f, 0.f, 0.f, 0.f};
    for (int t = wid; t < NT_; t += nw) {
        const unsigned short* ap = hb16 + ((size_t)t * 16 + c) * 64;
        short8 a0 = *(const short8*)(ap + g * 8);
        short8 a1 = *(const short8*)(ap + 32 + g * 8);
        f32x4 acc[4];
#pragma unroll
        for (int nt = 0; nt < 4; ++nt) {
            acc[nt] = __builtin_amdgcn_mfma_f32_16x16x32_bf16(a0, bf[nt][0], zero, 0, 0, 0);
            acc[nt] = __builtin_amdgcn_mfma_f32_16x16x32_bf16(a1, bf[nt][1], acc[nt], 0, 0, 0);
        }
#pragma unroll
        for (int r = 0; r < 4; ++r) {
            size_t row = (size_t)t * 16 + 4 * g + r;
#pragma unroll
            for (int nt = 0; nt < 4; ++nt)
                tdb[row * 64 + nt * 16 + c] = f2bf(acc[nt][r] + mbv[nt]);
        }
    }
}

// ---------------- fused MFMA edge kernel (XCD-pinned, ballot segments) ----------------
__global__ __launch_bounds__(256) void k_edge_mfma(const unsigned short* __restrict__ hb16,
                                                   const unsigned short* __restrict__ tdb,
                                                   const int2* __restrict__ epair,
                                                   const float* __restrict__ mw,
                                                   float* __restrict__ agg) {
    int lane = threadIdx.x & 63;
    int g = lane >> 4, c = lane & 15;
    short8 bf[4][2];
#pragma unroll
    for (int nt = 0; nt < 4; ++nt)
#pragma unroll
        for (int ks = 0; ks < 2; ++ks)
#pragma unroll
            for (int j = 0; j < 8; ++j)
                bf[nt][ks][j] = (short)f2bf(mw[(ks * 32 + g * 8 + j) * 64 + nt * 16 + c]);

    int i = blockIdx.x;                       // 0..4999
    int b = (i & 7) >> 1;                     // batch (XCD-pinned pair)
    int o = ((i >> 3) << 1) | (i & 1);        // per-batch block ordinal 0..1249
    int w = threadIdx.x >> 6;
    const int2* pp = epair + (size_t)b * E_;
    const unsigned short* hbase = hb16 + (size_t)(b * N_) * 64;
    const unsigned short* tbase = tdb + (size_t)(b * N_) * 64;
    float* abase = agg + (size_t)(b * N_) * 64;

    bool hi1 = (lane & 32) != 0;
    bool hi0 = (lane & 16) != 0;

    f32x4 zero = {0.f, 0.f, 0.f, 0.f};
#pragma unroll
    for (int k = 0; k < 4; ++k) {
        int t0 = (o * 4 + w) + k * 5000;      // tile 0..19999 within batch
        int s0 = t0 * 16;
        int2 pr = pp[s0 + c];
        int src = pr.x;
        int dval = pr.y;
        const unsigned short* hrow = hbase + (size_t)src * 64;
        short8 a0 = *(const short8*)(hrow + g * 8);
        short8 a1 = *(const short8*)(hrow + 32 + g * 8);

        f32x4 acc[4];
#pragma unroll
        for (int nt = 0; nt < 4; ++nt) {
            acc[nt] = __builtin_amdgcn_mfma_f32_16x16x32_bf16(a0, bf[nt][0], zero, 0, 0, 0);
            acc[nt] = __builtin_amdgcn_mfma_f32_16x16x32_bf16(a1, bf[nt][1], acc[nt], 0, 0, 0);
        }

        // segment head mask via ballot (sorted dst runs)
        int prev = __shfl(dval, (lane + 63) & 63);
        bool head = (c == 0) || (dval != prev);
        unsigned long long bal = __ballot(head);
        unsigned m16 = (unsigned)(bal & 0xFFFFu);

        while (m16) {
            int ii = __ffs(m16) - 1;
            unsigned rest = m16 & (m16 - 1);
            int jj = rest ? (__ffs(rest) - 1) : 16;
            m16 = rest;
            int d = __shfl(dval, ii);

            // tdst row for this segment (4 loads/lane, L2-pinned)
            const unsigned short* trow = tbase + (size_t)d * 64;
            float t0v = bf2f(trow[c]);
            float t1v = bf2f(trow[16 + c]);
            float t2v = bf2f(trow[32 + c]);
            float t3v = bf2f(trow[48 + c]);

            // masked relu-sum over this segment's rows owned by this lane
            float v0 = 0.f, v1 = 0.f, v2 = 0.f, v3 = 0.f;
#pragma unroll
            for (int r = 0; r < 4; ++r) {
                int rr = 4 * g + r;
                bool in = (rr >= ii) && (rr < jj);
                v0 += in ? fmaxf(acc[0][r] + t0v, 0.f) : 0.f;
                v1 += in ? fmaxf(acc[1][r] + t1v, 0.f) : 0.f;
                v2 += in ? fmaxf(acc[2][r] + t2v, 0.f) : 0.f;
                v3 += in ? fmaxf(acc[3][r] + t3v, 0.f) : 0.f;
            }
            // 3-shfl butterfly transpose-reduce: group g ends with total for nt=g
            float sA0 = hi1 ? v0 : v2;
            float sA1 = hi1 ? v1 : v3;
            float rA0 = __shfl_xor(sA0, 32);
            float rA1 = __shfl_xor(sA1, 32);
            float w0 = (hi1 ? v2 : v0) + rA0;
            float w1 = (hi1 ? v3 : v1) + rA1;
            float sB = hi0 ? w0 : w1;
            float rB = __shfl_xor(sB, 16);
            float outv = (hi0 ? w1 : w0) + rB;

            atomicAdd(&abase[(size_t)d * 64 + lane], outv);
        }
    }
}

// ---------------- h(bf16) += relu([h,agg] @ upd_w + upd_b) (MFMA) ----------------
__global__ __launch_bounds__(256) void k_upd_mfma(unsigned short* __restrict__ hb16,
                                                  const float* __restrict__ agg,
                                                  const float* __restrict__ uw,
                                                  const float* __restrict__ ub) {
    int lane = threadIdx.x & 63;
    int g = lane >> 4, c = lane & 15;
    short8 bh[4][2], ba[4][2];
#pragma unroll
    for (int nt = 0; nt < 4; ++nt)
#pragma unroll
        for (int ks = 0; ks < 2; ++ks)
#pragma unroll
            for (int j = 0; j < 8; ++j) {
                bh[nt][ks][j] = (short)f2bf(uw[(ks * 32 + g * 8 + j) * 64 + nt * 16 + c]);
                ba[nt][ks][j] = (short)f2bf(uw[(64 + ks * 32 + g * 8 + j) * 64 + nt * 16 + c]);
            }
    float ubv[4];
#pragma unroll
    for (int nt = 0; nt < 4; ++nt) ubv[nt] = ub[nt * 16 + c];

    int wid = blockIdx.x * 4 + (threadIdx.x >> 6);
    int nw = gridDim.x * 4;
    f32x4 zero = {0.f, 0.f, 0.f, 0.f};
    for (int t = wid; t < NT_; t += nw) {
        unsigned short* ap = hb16 + ((size_t)t * 16 + c) * 64;
        short8 a0 = *(const short8*)(ap + g * 8);
        short8 a1 = *(const short8*)(ap + 32 + g * 8);

        const float* gp = agg + ((size_t)t * 16 + c) * 64;
        float4 q0 = *(const float4*)(gp + g * 8);
        float4 q1 = *(const float4*)(gp + g * 8 + 4);
        float4 q2 = *(const float4*)(gp + 32 + g * 8);
        float4 q3 = *(const float4*)(gp + 32 + g * 8 + 4);
        short8 s0, s1;
        s0[0] = (short)f2bf(q0.x); s0[1] = (short)f2bf(q0.y);
        s0[2] = (short)f2bf(q0.z); s0[3] = (short)f2bf(q0.w);
        s0[4] = (short)f2bf(q1.x); s0[5] = (short)f2bf(q1.y);
        s0[6] = (short)f2bf(q1.z); s0[7] = (short)f2bf(q1.w);
        s1[0] = (short)f2bf(q2.x); s1[1] = (short)f2bf(q2.y);
        s1[2] = (short)f2bf(q2.z); s1[3] = (short)f2bf(q2.w);
        s1[4] = (short)f2bf(q3.x); s1[5] = (short)f2bf(q3.y);
        s1[6] = (short)f2bf(q3.z); s1[7] = (short)f2bf(q3.w);

        f32x4 acc[4];
#pragma unroll
        for (int nt = 0; nt < 4; ++nt) {
            acc[nt] = __builtin_amdgcn_mfma_f32_16x16x32_bf16(a0, bh[nt][0], zero, 0, 0, 0);
            acc[nt] = __builtin_amdgcn_mfma_f32_16x16x32_bf16(a1, bh[nt][1], acc[nt], 0, 0, 0);
            acc[nt] = __builtin_amdgcn_mfma_f32_16x16x32_bf16(s0, ba[nt][0], acc[nt], 0, 0, 0);
            acc[nt] = __builtin_amdgcn_mfma_f32_16x16x32_bf16(s1, ba[nt][1], acc[nt], 0, 0, 0);
        }
#pragma unroll
        for (int r = 0; r < 4; ++r) {
            size_t row = (size_t)t * 16 + 4 * g + r;
#pragma unroll
            for (int nt = 0; nt < 4; ++nt) {
                size_t idx = row * 64 + nt * 16 + c;
                float v = bf2f(hb16[idx]) + fmaxf(acc[nt][r] + ubv[nt], 0.f);
                hb16[idx] = f2bf(v);
            }
        }
    }
}

// ---------------- k/v projections (MFMA, bf16 out) ----------------
__global__ __launch_bounds__(256) void k_kv_mfma(const unsigned short* __restrict__ hb16,
                                                 const float* __restrict__ wk,
                                                 const float* __restrict__ bk,
                                                 const float* __restrict__ wv,
                                                 const float* __restrict__ bv,
                                                 unsigned short* __restrict__ kb16,
                                                 unsigned short* __restrict__ vb16) {
    int lane = threadIdx.x & 63;
    int g = lane >> 4, c = lane & 15;
    short8 bkf[4][2], bvf[4][2];
#pragma unroll
    for (int nt = 0; nt < 4; ++nt)
#pragma unroll
        for (int ks = 0; ks < 2; ++ks)
#pragma unroll
            for (int j = 0; j < 8; ++j) {
                bkf[nt][ks][j] = (short)f2bf(wk[(ks * 32 + g * 8 + j) * 64 + nt * 16 + c]);
                bvf[nt][ks][j] = (short)f2bf(wv[(ks * 32 + g * 8 + j) * 64 + nt * 16 + c]);
            }
    float bkv[4], bvv[4];
#pragma unroll
    for (int nt = 0; nt < 4; ++nt) { bkv[nt] = bk[nt * 16 + c]; bvv[nt] = bv[nt * 16 + c]; }

    int wid = blockIdx.x * 4 + (threadIdx.x >> 6);
    int nw = gridDim.x * 4;
    f32x4 zero = {0.f, 0.f, 0.f, 0.f};
    for (int t = wid; t < NT_; t += nw) {
        const unsigned short* ap = hb16 + ((size_t)t * 16 + c) * 64;
        short8 a0 = *(const short8*)(ap + g * 8);
        short8 a1 = *(const short8*)(ap + 32 + g * 8);
        f32x4 ak[4], av[4];
#pragma unroll
        for (int nt = 0; nt < 4; ++nt) {
            ak[nt] = __builtin_amdgcn_mfma_f32_16x16x32_bf16(a0, bkf[nt][0], zero, 0, 0, 0);
            ak[nt] = __builtin_amdgcn_mfma_f32_16x16x32_bf16(a1, bkf[nt][1], ak[nt], 0, 0, 0);
            av[nt] = __builtin_amdgcn_mfma_f32_16x16x32_bf16(a0, bvf[nt][0], zero, 0, 0, 0);
            av[nt] = __builtin_amdgcn_mfma_f32_16x16x32_bf16(a1, bvf[nt][1], av[nt], 0, 0, 0);
        }
#pragma unroll
        for (int r = 0; r < 4; ++r) {
            size_t row = (size_t)t * 16 + 4 * g + r;
#pragma unroll
            for (int nt = 0; nt < 4; ++nt) {
                kb16[row * 64 + nt * 16 + c] = f2bf(ak[nt][r] + bkv[nt]);
                vb16[row * 64 + nt * 16 + c] = f2bf(av[nt][r] + bvv[nt]);
            }
        }
    }
}

// ---------------- a = relu(ad @ w_ad + b_ad); q = a @ wq + bq ----------------
__global__ __launch_bounds__(64) void k_aq(const float* __restrict__ ad,
                                           const float* __restrict__ wad,
                                           const float* __restrict__ bad,
                                           const float* __restrict__ wq,
                                           const float* __restrict__ bq,
                                           float* __restrict__ a_out,
                                           float* __restrict__ q_out) {
    int b = blockIdx.x, t = threadIdx.x;
    __shared__ float sa[64];
    float acc = bad[t];
#pragma unroll
    for (int i = 0; i < 8; ++i) acc = fmaf(ad[b * 8 + i], wad[i * 64 + t], acc);
    float av = fmaxf(acc, 0.f);
    sa[t] = av;
    a_out[b * 64 + t] = av;
    __syncthreads();
    float qa = bq[t];
    for (int i = 0; i < 64; ++i) qa = fmaf(sa[i], wq[i * 64 + t], qa);
    q_out[b * 64 + t] = qa;
}

// ---------------- attention: chunked online softmax partials (bf16 k/v) ----------------
__global__ __launch_bounds__(256) void k_attn(const float* __restrict__ q,
                                              const unsigned short* __restrict__ kb16,
                                              const unsigned short* __restrict__ vb16,
                                              float* __restrict__ part) {
    int id = blockIdx.x;
    int ch = id % NCH;
    int bh = id / NCH;
    int b = bh / HEADS_, hd = bh % HEADS_;
    float qv[16];
#pragma unroll
    for (int d = 0; d < 16; ++d) qv[d] = q[b * 64 + hd * 16 + d];
    float m = -1e30f, s = 0.f, c[16];
#pragma unroll
    for (int d = 0; d < 16; ++d) c[d] = 0.f;
    int n0 = ch * CS;
    int n1 = n0 + CS; if (n1 > N_) n1 = N_;
    for (int n = n0 + threadIdx.x; n < n1; n += 256) {
        const short8* kr = (const short8*)(kb16 + ((size_t)b * N_ + n) * 64 + hd * 16);
        short8 k0 = kr[0], k1 = kr[1];
        float dot = 0.f;
#pragma unroll
        for (int d = 0; d < 8; ++d) {
            dot = fmaf(qv[d], bf2f((unsigned short)k0[d]), dot);
            dot = fmaf(qv[8 + d], bf2f((unsigned short)k1[d]), dot);
        }
        dot *= 0.25f;
        float nm = fmaxf(m, dot);
        float p = __expf(dot - nm);
        float cor = __expf(m - nm);
        const short8* vr = (const short8*)(vb16 + ((size_t)b * N_ + n) * 64 + hd * 16);
        short8 v0 = vr[0], v1 = vr[1];
        s = s * cor + p;
#pragma unroll
        for (int d = 0; d < 8; ++d) {
            c[d] = c[d] * cor + p * bf2f((unsigned short)v0[d]);
            c[8 + d] = c[8 + d] * cor + p * bf2f((unsigned short)v1[d]);
        }
        m = nm;
    }
#pragma unroll
    for (int o = 1; o < 64; o <<= 1) {
        float m2 = __shfl_xor(m, o);
        float s2 = __shfl_xor(s, o);
        float nm = fmaxf(m, m2);
        float w1 = __expf(m - nm), w2 = __expf(m2 - nm);
        s = s * w1 + s2 * w2;
#pragma unroll
        for (int d = 0; d < 16; ++d) {
            float c2 = __shfl_xor(c[d], o);
            c[d] = c[d] * w1 + c2 * w2;
        }
        m = nm;
    }
    __shared__ float red[4][18];
    int wv_ = threadIdx.x >> 6, lane = threadIdx.x & 63;
    if (lane == 0) {
        red[wv_][0] = m; red[wv_][1] = s;
#pragma unroll
        for (int d = 0; d < 16; ++d) red[wv_][2 + d] = c[d];
    }
    __syncthreads();
    if (threadIdx.x == 0) {
        float gm = red[0][0];
        for (int w = 1; w < 4; ++w) gm = fmaxf(gm, red[w][0]);
        float gs = 0.f, gc[16];
#pragma unroll
        for (int d = 0; d < 16; ++d) gc[d] = 0.f;
        for (int w = 0; w < 4; ++w) {
            float ww = __expf(red[w][0] - gm);
            gs += red[w][1] * ww;
#pragma unroll
            for (int d = 0; d < 16; ++d) gc[d] += red[w][2 + d] * ww;
        }
        float* p = part + (size_t)id * 18;
        p[0] = gm; p[1] = gs;
#pragma unroll
        for (int d = 0; d < 16; ++d) p[2 + d] = gc[d];
    }
}

__global__ __launch_bounds__(64) void k_comb(const float* __restrict__ part,
                                             float* __restrict__ ctx) {
    int bh = blockIdx.x, t = threadIdx.x;
    int b = bh / HEADS_, hd = bh % HEADS_;
    const float* p = part + ((size_t)bh * NCH + t) * 18;
    float m = p[0], s = p[1], c[16];
#pragma unroll
    for (int d = 0; d < 16; ++d) c[d] = p[2 + d];
    float gm = m;
#pragma unroll
    for (int o = 1; o < 64; o <<= 1) gm = fmaxf(gm, __shfl_xor(gm, o));
    float w = __expf(m - gm);
    float sw = s * w;
#pragma unroll
    for (int o = 1; o < 64; o <<= 1) sw += __shfl_xor(sw, o);
    float cg[16];
#pragma unroll
    for (int d = 0; d < 16; ++d) {
        float x = c[d] * w;
#pragma unroll
        for (int o = 1; o < 64; o <<= 1) x += __shfl_xor(x, o);
        cg[d] = x;
    }
    if (t == 0) {
#pragma unroll
        for (int d = 0; d < 16; ++d) ctx[b * 64 + hd * 16 + d] = cg[d] / sw;
    }
}

// ---------------- g = LN(a + ctx@wo + bo); wcomb = g/8 + policy_w ----------------
__global__ __launch_bounds__(64) void k_g(const float* __restrict__ a,
                                          const float* __restrict__ ctx,
                                          const float* __restrict__ wo,
                                          const float* __restrict__ bo,
                                          const float* __restrict__ lng,
                                          const float* __restrict__ lnb,
                                          const float* __restrict__ pw,
                                          float* __restrict__ wcomb) {
    int b = blockIdx.x, t = threadIdx.x;
    __shared__ float sc[64];
    sc[t] = ctx[b * 64 + t];
    __syncthreads();
    float o = bo[t];
    for (int i = 0; i < 64; ++i) o = fmaf(sc[i], wo[i * 64 + t], o);
    float y = a[b * 64 + t] + o;
    float mu = y;
#pragma unroll
    for (int oo = 1; oo < 64; oo <<= 1) mu += __shfl_xor(mu, oo);
    mu *= (1.f / 64.f);
    float d = y - mu;
    float var = d * d;
#pragma unroll
    for (int oo = 1; oo < 64; oo <<= 1) var += __shfl_xor(var, oo);
    var *= (1.f / 64.f);
    float g = d * rsqrtf(var + 1e-5f) * lng[t] + lnb[t];
    wcomb[b * 64 + t] = g * 0.125f + pw[t];
}

// ---------------- logits (bf16 h) ----------------
__global__ __launch_bounds__(256) void k_final(const unsigned short* __restrict__ hb16,
                                               const float* __restrict__ wcomb,
                                               const float* __restrict__ pb,
                                               const void* __restrict__ mask,
                                               const int* __restrict__ flagp,
                                               float* __restrict__ out) {
    int idx = blockIdx.x * 256 + threadIdx.x;
    if (idx >= B_ * N_) return;
    int b = idx / N_;
    const float* wr = wcomb + b * 64;
    const short8* hr = (const short8*)(hb16 + (size_t)idx * 64);
    float acc = pb[0];
#pragma unroll
    for (int i = 0; i < 8; ++i) {
        short8 hv = hr[i];
#pragma unroll
        for (int j = 0; j < 8; ++j)
            acc = fmaf(bf2f((unsigned short)hv[j]), wr[i * 8 + j], acc);
    }
    int flag = *flagp;
    bool mv;
    if (flag == 1)      mv = ((const int*)mask)[idx] != 0;
    else if (flag == 2) mv = ((const float*)mask)[idx] != 0.f;
    else                mv = ((const unsigned char*)mask)[idx] != 0;
    out[idx] = mv ? acc : -1.0e9f;
}

extern "C" void kernel_launch(void* const* d_in, const int* in_sizes, int n_in,
                              void* d_out, int out_size, void* d_ws, size_t ws_size,
                              hipStream_t stream) {
    const float* gn   = (const float*)d_in[0];
    const float* ad   = (const float*)d_in[1];
    const float* wnod = (const float*)d_in[2];
    const float* bnod = (const float*)d_in[3];
    const float* msgw = (const float*)d_in[4];
    const float* msgb = (const float*)d_in[5];
    const float* updw = (const float*)d_in[6];
    const float* updb = (const float*)d_in[7];
    const float* wad  = (const float*)d_in[8];
    const float* bad  = (const float*)d_in[9];
    const float* wq   = (const float*)d_in[10];
    const float* bq   = (const float*)d_in[11];
    const float* wk   = (const float*)d_in[12];
    const float* bk   = (const float*)d_in[13];
    const float* wv   = (const float*)d_in[14];
    const float* bv   = (const float*)d_in[15];
    const float* wo   = (const float*)d_in[16];
    const float* bo   = (const float*)d_in[17];
    const float* lng  = (const float*)d_in[18];
    const float* lnb  = (const float*)d_in[19];
    const float* pw   = (const float*)d_in[20];
    const float* pb   = (const float*)d_in[21];
    const int*   links= (const int*)d_in[22];
    const void*  mask = d_in[23];

    char* ws = (char*)d_ws;
    unsigned short* tdb  = (unsigned short*)(ws + OFF_A1);
    unsigned short* kb16 = (unsigned short*)(ws + OFF_A1);
    float* agg  = (float*)(ws + OFF_A2);
    unsigned short* vb16 = (unsigned short*)(ws + OFF_A2);
    int*   cnt  = (int*)(ws + OFF_CNT);
    int*   pos  = (int*)(ws + OFF_POS);
    int*   offs = (int*)(ws + OFF_OFFS);
    int2*  epair= (int2*)(ws + OFF_EPAIR);
    unsigned short* hb16 = (unsigned short*)(ws + OFF_HB16);
    float* avec = (float*)(ws + OFF_AVEC);
    float* qvec = (float*)(ws + OFF_Q);
    float* ctx  = (float*)(ws + OFF_CTX);
    float* wcmb = (float*)(ws + OFF_WCMB);
    int*   flag = (int*)(ws + OFF_FLAG);
    float* part = (float*)(ws + OFF_PART);
    float* out  = (float*)d_out;

    hipMemsetAsync(cnt, 0, (size_t)B_ * N_ * 4, stream);
    k_maskdetect<<<1, 1, 0, stream>>>((const unsigned int*)mask, flag);
    k_embed<<<4096, 256, 0, stream>>>(gn, wnod, bnod, hb16);
    k_count<<<5000, 256, 0, stream>>>(links, cnt);
    k_scan<<<B_, 1024, 0, stream>>>(cnt, offs, pos);
    k_fill<<<5000, 256, 0, stream>>>(links, pos, epair);

    for (int l = 0; l < 2; ++l) {
        const float* mwl = msgw + (size_t)l * 128 * 64;
        const float* mbl = msgb + (size_t)l * 64;
        const float* uwl = updw + (size_t)l * 128 * 64;
        const float* ubl = updb + (size_t)l * 64;
        k_tdst_mfma<<<512, 256, 0, stream>>>(hb16, mwl, mbl, tdb);
        hipMemsetAsync(agg, 0, HB, stream);
        k_edge_mfma<<<5000, 256, 0, stream>>>(hb16, tdb, epair, mwl, agg);
        k_upd_mfma<<<512, 256, 0, stream>>>(hb16, agg, uwl, ubl);
    }

    k_aq<<<B_, 64, 0, stream>>>(ad, wad, bad, wq, bq, avec, qvec);
    k_kv_mfma<<<512, 256, 0, stream>>>(hb16, wk, bk, wv, bv, kb16, vb16);
    k_attn<<<B_ * HEADS_ * NCH, 256, 0, stream>>>(qvec, kb16, vb16, part);
    k_comb<<<B_ * HEADS_, 64, 0, stream>>>(part, ctx);
    k_g<<<B_, 64, 0, stream>>>(avec, ctx, wo, bo, lng, lnb, pw, wcmb);
    k_final<<<(B_ * N_ + 255) / 256, 256, 0, stream>>>(hb16, wcmb, pb, mask, flag, out);
}

// Round 8
// 398.814 us; speedup vs baseline: 2.0351x; 1.0227x over previous
//
#include <hip/hip_runtime.h>
#include <hip/hip_bf16.h>
#include <math.h>

// Problem constants
constexpr int B_ = 4;
constexpr int N_ = 20000;
constexpr int E_ = 320000;
constexpr int HEADS_ = 4;
constexpr int NCH = 64;                       // attention chunks per (b,head)
constexpr int CS = (N_ + NCH - 1) / NCH;      // 313
constexpr int NT_ = (B_ * N_) / 16;           // 5000 node tiles

typedef __attribute__((ext_vector_type(8))) short short8;   // 8 bf16
typedef __attribute__((ext_vector_type(4))) float f32x4;

// Workspace layout (bytes). ~84 MB.
constexpr size_t HB = (size_t)B_ * N_ * 64 * 4;      // 20,480,000
constexpr size_t OFF_A1   = HB;            // tdb (bf16), later kb16
constexpr size_t OFF_A2   = 2 * HB;        // agg (f32), later vb16
constexpr size_t OFF_CNT  = 3 * HB;                          // B*N ints
constexpr size_t OFF_POS  = OFF_CNT + (size_t)B_ * N_ * 4;   // B*N ints
constexpr size_t OFF_OFFS = OFF_POS + (size_t)B_ * N_ * 4;   // B*(N+1) ints
constexpr size_t OFF_EPAIR= OFF_OFFS + ((size_t)B_ * (N_ + 1) * 4 + 64); // B*E int2
constexpr size_t OFF_HB16 = OFF_EPAIR + (size_t)B_ * E_ * 8; // B*N*64 bf16
constexpr size_t OFF_AVEC = OFF_HB16 + (size_t)B_ * N_ * 64 * 2;
constexpr size_t OFF_Q    = OFF_AVEC + 1024;
constexpr size_t OFF_CTX  = OFF_Q + 1024;
constexpr size_t OFF_WCMB = OFF_CTX + 1024;
constexpr size_t OFF_FLAG = OFF_WCMB + 1024;
constexpr size_t OFF_PART = OFF_FLAG + 64;                   // 1024*18 f partials

static __device__ __forceinline__ unsigned short f2bf(float f) {
    union { float f; unsigned u; } v; v.f = f;
    unsigned r = v.u + 0x7fffu + ((v.u >> 16) & 1u);
    return (unsigned short)(r >> 16);
}
static __device__ __forceinline__ float bf2f(unsigned short u) {
    union { unsigned u; float f; } v; v.u = (unsigned)u << 16;
    return v.f;
}

// ---------------- mask dtype detection ----------------
__global__ void k_maskdetect(const unsigned int* __restrict__ m, int* __restrict__ flag) {
    if (blockIdx.x == 0 && threadIdx.x == 0) {
        bool alli = true, allf = true;
        for (int i = 0; i < 256; ++i) {
            unsigned v = m[i];
            alli = alli && (v <= 1u);
            allf = allf && (v == 0u || v == 0x3f800000u);
        }
        *flag = alli ? 1 : (allf ? 2 : 0);
    }
}

// ---------------- hb16 = bf16(relu(gn @ w_node + b_node)) ----------------
__global__ __launch_bounds__(256) void k_embed(const float* __restrict__ gn,
                                               const float* __restrict__ w,
                                               const float* __restrict__ bias,
                                               unsigned short* __restrict__ hb16) {
    int lane = threadIdx.x & 63;
    float wc[16];
#pragma unroll
    for (int i = 0; i < 16; ++i) wc[i] = w[i * 64 + lane];
    float bb = bias[lane];
    int gw = (blockIdx.x * blockDim.x + threadIdx.x) >> 6;
    int nw = (gridDim.x * blockDim.x) >> 6;
    for (int node = gw; node < B_ * N_; node += nw) {
        const float* r = gn + (size_t)node * 16;
        float a0 = 0.f, a1 = 0.f, a2 = 0.f, a3 = 0.f;
#pragma unroll
        for (int i = 0; i < 16; i += 4) {
            a0 = fmaf(r[i + 0], wc[i + 0], a0);
            a1 = fmaf(r[i + 1], wc[i + 1], a1);
            a2 = fmaf(r[i + 2], wc[i + 2], a2);
            a3 = fmaf(r[i + 3], wc[i + 3], a3);
        }
        float v = fmaxf(bb + ((a0 + a1) + (a2 + a3)), 0.f);
        hb16[(size_t)node * 64 + lane] = f2bf(v);
    }
}

// ---------------- CSR build (XCD-pinned per batch) ----------------
__global__ __launch_bounds__(256) void k_count(const int* __restrict__ links,
                                               int* __restrict__ cnt) {
    int i = blockIdx.x;                   // 0..4999
    int b = (i & 7) >> 1;
    int o = ((i >> 3) << 1) | (i & 1);    // 0..1249
    int e = o * 256 + threadIdx.x;
    int dst = links[(size_t)b * 2 * E_ + E_ + e];
    atomicAdd(&cnt[b * N_ + dst], 1);
}

// 1024-thread shuffle-based scan
__global__ __launch_bounds__(1024) void k_scan(const int* __restrict__ cnt,
                                               int* __restrict__ offs,
                                               int* __restrict__ pos) {
    __shared__ int wsum[16];
    __shared__ int sbase;
    int b = blockIdx.x, t = threadIdx.x;
    int lane = t & 63, wv = t >> 6;
    if (t == 0) { sbase = 0; offs[(size_t)b * (N_ + 1)] = 0; }
    __syncthreads();
    for (int base = 0; base < N_; base += 1024) {
        int idx = base + t;
        int c = (idx < N_) ? cnt[(size_t)b * N_ + idx] : 0;
        int x = c;
#pragma unroll
        for (int o = 1; o < 64; o <<= 1) {
            int y = __shfl_up(x, o);
            if (lane >= o) x += y;
        }
        if (lane == 63) wsum[wv] = x;
        __syncthreads();
        if (wv == 0) {
            int s = (lane < 16) ? wsum[lane] : 0;
#pragma unroll
            for (int o = 1; o < 16; o <<= 1) {
                int y = __shfl_up(s, o);
                if (lane >= o) s += y;
            }
            if (lane < 16) wsum[lane] = s;
        }
        __syncthreads();
        int wpre = (wv > 0) ? wsum[wv - 1] : 0;
        int incl = x + wpre + sbase;
        if (idx < N_) {
            offs[(size_t)b * (N_ + 1) + idx + 1] = incl;
            pos[(size_t)b * N_ + idx] = incl - c;
        }
        __syncthreads();
        if (t == 1023) sbase = incl;
        __syncthreads();
    }
}

// dst-windowed scatter: 10 passes over dst>>11 so each pass's store window
// (~256KB/batch) stays L2-resident until its lines are fully written.
__global__ __launch_bounds__(256) void k_fill(const int* __restrict__ links,
                                              int* __restrict__ pos,
                                              int2* __restrict__ epair) {
    int i = blockIdx.x;                   // 0..4999
    int b = (i & 7) >> 1;
    int o = ((i >> 3) << 1) | (i & 1);    // 0..1249
    int e = o * 256 + threadIdx.x;
    int src = links[(size_t)b * 2 * E_ + e];
    int dst = links[(size_t)b * 2 * E_ + E_ + e];
    int w = dst >> 11;                    // 0..9
    int2* ep = epair + (size_t)b * E_;
    int* pp = pos + b * N_;
#pragma unroll
    for (int p = 0; p < 10; ++p) {
        if (w == p) {
            int slot = atomicAdd(&pp[dst], 1);
            ep[slot] = make_int2(src, dst);
        }
    }
}

// ---------------- tdst = W2^T h + msg_b (MFMA node GEMM, bf16 out) ----------------
__global__ __launch_bounds__(256) void k_tdst_mfma(const unsigned short* __restrict__ hb16,
                                                   const float* __restrict__ mw,
                                                   const float* __restrict__ mb,
                                                   unsigned short* __restrict__ tdb) {
    int lane = threadIdx.x & 63;
    int g = lane >> 4, c = lane & 15;
    short8 bf[4][2];
#pragma unroll
    for (int nt = 0; nt < 4; ++nt)
#pragma unroll
        for (int ks = 0; ks < 2; ++ks)
#pragma unroll
            for (int j = 0; j < 8; ++j)
                bf[nt][ks][j] = (short)f2bf(mw[(64 + ks * 32 + g * 8 + j) * 64 + nt * 16 + c]);
    float mbv[4];
#pragma unroll
    for (int nt = 0; nt < 4; ++nt) mbv[nt] = mb[nt * 16 + c];

    int wid = blockIdx.x * 4 + (threadIdx.x >> 6);
    int nw = gridDim.x * 4;
    f32x4 zero = {0.f, 0.f, 0.f, 0.f};
    for (int t = wid; t < NT_; t += nw) {
        const unsigned short* ap = hb16 + ((size_t)t * 16 + c) * 64;
        short8 a0 = *(const short8*)(ap + g * 8);
        short8 a1 = *(const short8*)(ap + 32 + g * 8);
        f32x4 acc[4];
#pragma unroll
        for (int nt = 0; nt < 4; ++nt) {
            acc[nt] = __builtin_amdgcn_mfma_f32_16x16x32_bf16(a0, bf[nt][0], zero, 0, 0, 0);
            acc[nt] = __builtin_amdgcn_mfma_f32_16x16x32_bf16(a1, bf[nt][1], acc[nt], 0, 0, 0);
        }
#pragma unroll
        for (int r = 0; r < 4; ++r) {
            size_t row = (size_t)t * 16 + 4 * g + r;
#pragma unroll
            for (int nt = 0; nt < 4; ++nt)
                tdb[row * 64 + nt * 16 + c] = f2bf(acc[nt][r] + mbv[nt]);
        }
    }
}

// ---------------- fused MFMA edge kernel (XCD-pinned, hoisted gathers) ----------------
__global__ __launch_bounds__(256) void k_edge_mfma(const unsigned short* __restrict__ hb16,
                                                   const unsigned short* __restrict__ tdb,
                                                   const int2* __restrict__ epair,
                                                   const float* __restrict__ mw,
                                                   float* __restrict__ agg) {
    int lane = threadIdx.x & 63;
    int g = lane >> 4, c = lane & 15;
    short8 bf[4][2];
#pragma unroll
    for (int nt = 0; nt < 4; ++nt)
#pragma unroll
        for (int ks = 0; ks < 2; ++ks)
#pragma unroll
            for (int j = 0; j < 8; ++j)
                bf[nt][ks][j] = (short)f2bf(mw[(ks * 32 + g * 8 + j) * 64 + nt * 16 + c]);

    int i = blockIdx.x;                       // 0..4999
    int b = (i & 7) >> 1;                     // batch (XCD-pinned pair)
    int o = ((i >> 3) << 1) | (i & 1);        // per-batch block ordinal 0..1249
    int w = threadIdx.x >> 6;
    const int2* pp = epair + (size_t)b * E_;
    const unsigned short* hbase = hb16 + (size_t)(b * N_) * 64;
    const unsigned short* tbase = tdb + (size_t)(b * N_) * 64;
    float* abase = agg + (size_t)(b * N_) * 64;

    bool hi1 = (lane & 32) != 0;
    bool hi0 = (lane & 16) != 0;

    // hoisted loads: all 4 tiles' epair + hb16 gathers issue before any compute
    int2 pr[4];
#pragma unroll
    for (int k = 0; k < 4; ++k) {
        int t0 = (o * 4 + w) + k * 5000;
        pr[k] = pp[t0 * 16 + c];
    }
    short8 a0[4], a1[4];
#pragma unroll
    for (int k = 0; k < 4; ++k) {
        const unsigned short* hrow = hbase + (size_t)pr[k].x * 64;
        a0[k] = *(const short8*)(hrow + g * 8);
        a1[k] = *(const short8*)(hrow + 32 + g * 8);
    }

    f32x4 zero = {0.f, 0.f, 0.f, 0.f};
#pragma unroll
    for (int k = 0; k < 4; ++k) {
        int dval = pr[k].y;
        f32x4 acc[4];
#pragma unroll
        for (int nt = 0; nt < 4; ++nt) {
            acc[nt] = __builtin_amdgcn_mfma_f32_16x16x32_bf16(a0[k], bf[nt][0], zero, 0, 0, 0);
            acc[nt] = __builtin_amdgcn_mfma_f32_16x16x32_bf16(a1[k], bf[nt][1], acc[nt], 0, 0, 0);
        }

        // segment head mask via ballot (sorted dst runs)
        int prev = __shfl(dval, (lane + 63) & 63);
        bool head = (c == 0) || (dval != prev);
        unsigned long long bal = __ballot(head);
        unsigned m16 = (unsigned)(bal & 0xFFFFu);

        while (m16) {
            int ii = __ffs(m16) - 1;
            unsigned rest = m16 & (m16 - 1);
            int jj = rest ? (__ffs(rest) - 1) : 16;
            m16 = rest;
            int d = __shfl(dval, ii);

            const unsigned short* trow = tbase + (size_t)d * 64;
            float t0v = bf2f(trow[c]);
            float t1v = bf2f(trow[16 + c]);
            float t2v = bf2f(trow[32 + c]);
            float t3v = bf2f(trow[48 + c]);

            float v0 = 0.f, v1 = 0.f, v2 = 0.f, v3 = 0.f;
#pragma unroll
            for (int r = 0; r < 4; ++r) {
                int rr = 4 * g + r;
                bool in = (rr >= ii) && (rr < jj);
                v0 += in ? fmaxf(acc[0][r] + t0v, 0.f) : 0.f;
                v1 += in ? fmaxf(acc[1][r] + t1v, 0.f) : 0.f;
                v2 += in ? fmaxf(acc[2][r] + t2v, 0.f) : 0.f;
                v3 += in ? fmaxf(acc[3][r] + t3v, 0.f) : 0.f;
            }
            float sA0 = hi1 ? v0 : v2;
            float sA1 = hi1 ? v1 : v3;
            float rA0 = __shfl_xor(sA0, 32);
            float rA1 = __shfl_xor(sA1, 32);
            float w0 = (hi1 ? v2 : v0) + rA0;
            float w1 = (hi1 ? v3 : v1) + rA1;
            float sB = hi0 ? w0 : w1;
            float rB = __shfl_xor(sB, 16);
            float outv = (hi0 ? w1 : w0) + rB;

            atomicAdd(&abase[(size_t)d * 64 + lane], outv);
        }
    }
}

// ---------------- h(bf16) += relu([h,agg] @ upd_w + upd_b) (MFMA) ----------------
__global__ __launch_bounds__(256) void k_upd_mfma(unsigned short* __restrict__ hb16,
                                                  const float* __restrict__ agg,
                                                  const float* __restrict__ uw,
                                                  const float* __restrict__ ub) {
    int lane = threadIdx.x & 63;
    int g = lane >> 4, c = lane & 15;
    short8 bh[4][2], ba[4][2];
#pragma unroll
    for (int nt = 0; nt < 4; ++nt)
#pragma unroll
        for (int ks = 0; ks < 2; ++ks)
#pragma unroll
            for (int j = 0; j < 8; ++j) {
                bh[nt][ks][j] = (short)f2bf(uw[(ks * 32 + g * 8 + j) * 64 + nt * 16 + c]);
                ba[nt][ks][j] = (short)f2bf(uw[(64 + ks * 32 + g * 8 + j) * 64 + nt * 16 + c]);
            }
    float ubv[4];
#pragma unroll
    for (int nt = 0; nt < 4; ++nt) ubv[nt] = ub[nt * 16 + c];

    int wid = blockIdx.x * 4 + (threadIdx.x >> 6);
    int nw = gridDim.x * 4;
    f32x4 zero = {0.f, 0.f, 0.f, 0.f};
    for (int t = wid; t < NT_; t += nw) {
        unsigned short* ap = hb16 + ((size_t)t * 16 + c) * 64;
        short8 a0 = *(const short8*)(ap + g * 8);
        short8 a1 = *(const short8*)(ap + 32 + g * 8);

        const float* gp = agg + ((size_t)t * 16 + c) * 64;
        float4 q0 = *(const float4*)(gp + g * 8);
        float4 q1 = *(const float4*)(gp + g * 8 + 4);
        float4 q2 = *(const float4*)(gp + 32 + g * 8);
        float4 q3 = *(const float4*)(gp + 32 + g * 8 + 4);
        short8 s0, s1;
        s0[0] = (short)f2bf(q0.x); s0[1] = (short)f2bf(q0.y);
        s0[2] = (short)f2bf(q0.z); s0[3] = (short)f2bf(q0.w);
        s0[4] = (short)f2bf(q1.x); s0[5] = (short)f2bf(q1.y);
        s0[6] = (short)f2bf(q1.z); s0[7] = (short)f2bf(q1.w);
        s1[0] = (short)f2bf(q2.x); s1[1] = (short)f2bf(q2.y);
        s1[2] = (short)f2bf(q2.z); s1[3] = (short)f2bf(q2.w);
        s1[4] = (short)f2bf(q3.x); s1[5] = (short)f2bf(q3.y);
        s1[6] = (short)f2bf(q3.z); s1[7] = (short)f2bf(q3.w);

        f32x4 acc[4];
#pragma unroll
        for (int nt = 0; nt < 4; ++nt) {
            acc[nt] = __builtin_amdgcn_mfma_f32_16x16x32_bf16(a0, bh[nt][0], zero, 0, 0, 0);
            acc[nt] = __builtin_amdgcn_mfma_f32_16x16x32_bf16(a1, bh[nt][1], acc[nt], 0, 0, 0);
            acc[nt] = __builtin_amdgcn_mfma_f32_16x16x32_bf16(s0, ba[nt][0], acc[nt], 0, 0, 0);
            acc[nt] = __builtin_amdgcn_mfma_f32_16x16x32_bf16(s1, ba[nt][1], acc[nt], 0, 0, 0);
        }
#pragma unroll
        for (int r = 0; r < 4; ++r) {
            size_t row = (size_t)t * 16 + 4 * g + r;
#pragma unroll
            for (int nt = 0; nt < 4; ++nt) {
                size_t idx = row * 64 + nt * 16 + c;
                float v = bf2f(hb16[idx]) + fmaxf(acc[nt][r] + ubv[nt], 0.f);
                hb16[idx] = f2bf(v);
            }
        }
    }
}

// ---------------- k/v projections (MFMA, bf16 out) ----------------
__global__ __launch_bounds__(256) void k_kv_mfma(const unsigned short* __restrict__ hb16,
                                                 const float* __restrict__ wk,
                                                 const float* __restrict__ bk,
                                                 const float* __restrict__ wv,
                                                 const float* __restrict__ bv,
                                                 unsigned short* __restrict__ kb16,
                                                 unsigned short* __restrict__ vb16) {
    int lane = threadIdx.x & 63;
    int g = lane >> 4, c = lane & 15;
    short8 bkf[4][2], bvf[4][2];
#pragma unroll
    for (int nt = 0; nt < 4; ++nt)
#pragma unroll
        for (int ks = 0; ks < 2; ++ks)
#pragma unroll
            for (int j = 0; j < 8; ++j) {
                bkf[nt][ks][j] = (short)f2bf(wk[(ks * 32 + g * 8 + j) * 64 + nt * 16 + c]);
                bvf[nt][ks][j] = (short)f2bf(wv[(ks * 32 + g * 8 + j) * 64 + nt * 16 + c]);
            }
    float bkv[4], bvv[4];
#pragma unroll
    for (int nt = 0; nt < 4; ++nt) { bkv[nt] = bk[nt * 16 + c]; bvv[nt] = bv[nt * 16 + c]; }

    int wid = blockIdx.x * 4 + (threadIdx.x >> 6);
    int nw = gridDim.x * 4;
    f32x4 zero = {0.f, 0.f, 0.f, 0.f};
    for (int t = wid; t < NT_; t += nw) {
        const unsigned short* ap = hb16 + ((size_t)t * 16 + c) * 64;
        short8 a0 = *(const short8*)(ap + g * 8);
        short8 a1 = *(const short8*)(ap + 32 + g * 8);
        f32x4 ak[4], av[4];
#pragma unroll
        for (int nt = 0; nt < 4; ++nt) {
            ak[nt] = __builtin_amdgcn_mfma_f32_16x16x32_bf16(a0, bkf[nt][0], zero, 0, 0, 0);
            ak[nt] = __builtin_amdgcn_mfma_f32_16x16x32_bf16(a1, bkf[nt][1], ak[nt], 0, 0, 0);
            av[nt] = __builtin_amdgcn_mfma_f32_16x16x32_bf16(a0, bvf[nt][0], zero, 0, 0, 0);
            av[nt] = __builtin_amdgcn_mfma_f32_16x16x32_bf16(a1, bvf[nt][1], av[nt], 0, 0, 0);
        }
#pragma unroll
        for (int r = 0; r < 4; ++r) {
            size_t row = (size_t)t * 16 + 4 * g + r;
#pragma unroll
            for (int nt = 0; nt < 4; ++nt) {
                kb16[row * 64 + nt * 16 + c] = f2bf(ak[nt][r] + bkv[nt]);
                vb16[row * 64 + nt * 16 + c] = f2bf(av[nt][r] + bvv[nt]);
            }
        }
    }
}

// ---------------- a = relu(ad @ w_ad + b_ad); q = a @ wq + bq ----------------
__global__ __launch_bounds__(64) void k_aq(const float* __restrict__ ad,
                                           const float* __restrict__ wad,
                                           const float* __restrict__ bad,
                                           const float* __restrict__ wq,
                                           const float* __restrict__ bq,
                                           float* __restrict__ a_out,
                                           float* __restrict__ q_out) {
    int b = blockIdx.x, t = threadIdx.x;
    __shared__ float sa[64];
    float acc = bad[t];
#pragma unroll
    for (int i = 0; i < 8; ++i) acc = fmaf(ad[b * 8 + i], wad[i * 64 + t], acc);
    float av = fmaxf(acc, 0.f);
    sa[t] = av;
    a_out[b * 64 + t] = av;
    __syncthreads();
    float qa = bq[t];
    for (int i = 0; i < 64; ++i) qa = fmaf(sa[i], wq[i * 64 + t], qa);
    q_out[b * 64 + t] = qa;
}

// ---------------- attention: chunked online softmax partials (bf16 k/v) ----------------
__global__ __launch_bounds__(256) void k_attn(const float* __restrict__ q,
                                              const unsigned short* __restrict__ kb16,
                                              const unsigned short* __restrict__ vb16,
                                              float* __restrict__ part) {
    int id = blockIdx.x;
    int ch = id % NCH;
    int bh = id / NCH;
    int b = bh / HEADS_, hd = bh % HEADS_;
    float qv[16];
#pragma unroll
    for (int d = 0; d < 16; ++d) qv[d] = q[b * 64 + hd * 16 + d];
    float m = -1e30f, s = 0.f, c[16];
#pragma unroll
    for (int d = 0; d < 16; ++d) c[d] = 0.f;
    int n0 = ch * CS;
    int n1 = n0 + CS; if (n1 > N_) n1 = N_;
    for (int n = n0 + threadIdx.x; n < n1; n += 256) {
        const short8* kr = (const short8*)(kb16 + ((size_t)b * N_ + n) * 64 + hd * 16);
        short8 k0 = kr[0], k1 = kr[1];
        float dot = 0.f;
#pragma unroll
        for (int d = 0; d < 8; ++d) {
            dot = fmaf(qv[d], bf2f((unsigned short)k0[d]), dot);
            dot = fmaf(qv[8 + d], bf2f((unsigned short)k1[d]), dot);
        }
        dot *= 0.25f;
        float nm = fmaxf(m, dot);
        float p = __expf(dot - nm);
        float cor = __expf(m - nm);
        const short8* vr = (const short8*)(vb16 + ((size_t)b * N_ + n) * 64 + hd * 16);
        short8 v0 = vr[0], v1 = vr[1];
        s = s * cor + p;
#pragma unroll
        for (int d = 0; d < 8; ++d) {
            c[d] = c[d] * cor + p * bf2f((unsigned short)v0[d]);
            c[8 + d] = c[8 + d] * cor + p * bf2f((unsigned short)v1[d]);
        }
        m = nm;
    }
#pragma unroll
    for (int o = 1; o < 64; o <<= 1) {
        float m2 = __shfl_xor(m, o);
        float s2 = __shfl_xor(s, o);
        float nm = fmaxf(m, m2);
        float w1 = __expf(m - nm), w2 = __expf(m2 - nm);
        s = s * w1 + s2 * w2;
#pragma unroll
        for (int d = 0; d < 16; ++d) {
            float c2 = __shfl_xor(c[d], o);
            c[d] = c[d] * w1 + c2 * w2;
        }
        m = nm;
    }
    __shared__ float red[4][18];
    int wv_ = threadIdx.x >> 6, lane = threadIdx.x & 63;
    if (lane == 0) {
        red[wv_][0] = m; red[wv_][1] = s;
#pragma unroll
        for (int d = 0; d < 16; ++d) red[wv_][2 + d] = c[d];
    }
    __syncthreads();
    if (threadIdx.x == 0) {
        float gm = red[0][0];
        for (int w = 1; w < 4; ++w) gm = fmaxf(gm, red[w][0]);
        float gs = 0.f, gc[16];
#pragma unroll
        for (int d = 0; d < 16; ++d) gc[d] = 0.f;
        for (int w = 0; w < 4; ++w) {
            float ww = __expf(red[w][0] - gm);
            gs += red[w][1] * ww;
#pragma unroll
            for (int d = 0; d < 16; ++d) gc[d] += red[w][2 + d] * ww;
        }
        float* p = part + (size_t)id * 18;
        p[0] = gm; p[1] = gs;
#pragma unroll
        for (int d = 0; d < 16; ++d) p[2 + d] = gc[d];
    }
}

__global__ __launch_bounds__(64) void k_comb(const float* __restrict__ part,
                                             float* __restrict__ ctx) {
    int bh = blockIdx.x, t = threadIdx.x;
    int b = bh / HEADS_, hd = bh % HEADS_;
    const float* p = part + ((size_t)bh * NCH + t) * 18;
    float m = p[0], s = p[1], c[16];
#pragma unroll
    for (int d = 0; d < 16; ++d) c[d] = p[2 + d];
    float gm = m;
#pragma unroll
    for (int o = 1; o < 64; o <<= 1) gm = fmaxf(gm, __shfl_xor(gm, o));
    float w = __expf(m - gm);
    float sw = s * w;
#pragma unroll
    for (int o = 1; o < 64; o <<= 1) sw += __shfl_xor(sw, o);
    float cg[16];
#pragma unroll
    for (int d = 0; d < 16; ++d) {
        float x = c[d] * w;
#pragma unroll
        for (int o = 1; o < 64; o <<= 1) x += __shfl_xor(x, o);
        cg[d] = x;
    }
    if (t == 0) {
#pragma unroll
        for (int d = 0; d < 16; ++d) ctx[b * 64 + hd * 16 + d] = cg[d] / sw;
    }
}

// ---------------- g = LN(a + ctx@wo + bo); wcomb = g/8 + policy_w ----------------
__global__ __launch_bounds__(64) void k_g(const float* __restrict__ a,
                                          const float* __restrict__ ctx,
                                          const float* __restrict__ wo,
                                          const float* __restrict__ bo,
                                          const float* __restrict__ lng,
                                          const float* __restrict__ lnb,
                                          const float* __restrict__ pw,
                                          float* __restrict__ wcomb) {
    int b = blockIdx.x, t = threadIdx.x;
    __shared__ float sc[64];
    sc[t] = ctx[b * 64 + t];
    __syncthreads();
    float o = bo[t];
    for (int i = 0; i < 64; ++i) o = fmaf(sc[i], wo[i * 64 + t], o);
    float y = a[b * 64 + t] + o;
    float mu = y;
#pragma unroll
    for (int oo = 1; oo < 64; oo <<= 1) mu += __shfl_xor(mu, oo);
    mu *= (1.f / 64.f);
    float d = y - mu;
    float var = d * d;
#pragma unroll
    for (int oo = 1; oo < 64; oo <<= 1) var += __shfl_xor(var, oo);
    var *= (1.f / 64.f);
    float g = d * rsqrtf(var + 1e-5f) * lng[t] + lnb[t];
    wcomb[b * 64 + t] = g * 0.125f + pw[t];
}

// ---------------- logits (bf16 h) ----------------
__global__ __launch_bounds__(256) void k_final(const unsigned short* __restrict__ hb16,
                                               const float* __restrict__ wcomb,
                                               const float* __restrict__ pb,
                                               const void* __restrict__ mask,
                                               const int* __restrict__ flagp,
                                               float* __restrict__ out) {
    int idx = blockIdx.x * 256 + threadIdx.x;
    if (idx >= B_ * N_) return;
    int b = idx / N_;
    const float* wr = wcomb + b * 64;
    const short8* hr = (const short8*)(hb16 + (size_t)idx * 64);
    float acc = pb[0];
#pragma unroll
    for (int i = 0; i < 8; ++i) {
        short8 hv = hr[i];
#pragma unroll
        for (int j = 0; j < 8; ++j)
            acc = fmaf(bf2f((unsigned short)hv[j]), wr[i * 8 + j], acc);
    }
    int flag = *flagp;
    bool mv;
    if (flag == 1)      mv = ((const int*)mask)[idx] != 0;
    else if (flag == 2) mv = ((const float*)mask)[idx] != 0.f;
    else                mv = ((const unsigned char*)mask)[idx] != 0;
    out[idx] = mv ? acc : -1.0e9f;
}

extern "C" void kernel_launch(void* const* d_in, const int* in_sizes, int n_in,
                              void* d_out, int out_size, void* d_ws, size_t ws_size,
                              hipStream_t stream) {
    const float* gn   = (const float*)d_in[0];
    const float* ad   = (const float*)d_in[1];
    const float* wnod = (const float*)d_in[2];
    const float* bnod = (const float*)d_in[3];
    const float* msgw = (const float*)d_in[4];
    const float* msgb = (const float*)d_in[5];
    const float* updw = (const float*)d_in[6];
    const float* updb = (const float*)d_in[7];
    const float* wad  = (const float*)d_in[8];
    const float* bad  = (const float*)d_in[9];
    const float* wq   = (const float*)d_in[10];
    const float* bq   = (const float*)d_in[11];
    const float* wk   = (const float*)d_in[12];
    const float* bk   = (const float*)d_in[13];
    const float* wv   = (const float*)d_in[14];
    const float* bv   = (const float*)d_in[15];
    const float* wo   = (const float*)d_in[16];
    const float* bo   = (const float*)d_in[17];
    const float* lng  = (const float*)d_in[18];
    const float* lnb  = (const float*)d_in[19];
    const float* pw   = (const float*)d_in[20];
    const float* pb   = (const float*)d_in[21];
    const int*   links= (const int*)d_in[22];
    const void*  mask = d_in[23];

    char* ws = (char*)d_ws;
    unsigned short* tdb  = (unsigned short*)(ws + OFF_A1);
    unsigned short* kb16 = (unsigned short*)(ws + OFF_A1);
    float* agg  = (float*)(ws + OFF_A2);
    unsigned short* vb16 = (unsigned short*)(ws + OFF_A2);
    int*   cnt  = (int*)(ws + OFF_CNT);
    int*   pos  = (int*)(ws + OFF_POS);
    int*   offs = (int*)(ws + OFF_OFFS);
    int2*  epair= (int2*)(ws + OFF_EPAIR);
    unsigned short* hb16 = (unsigned short*)(ws + OFF_HB16);
    float* avec = (float*)(ws + OFF_AVEC);
    float* qvec = (float*)(ws + OFF_Q);
    float* ctx  = (float*)(ws + OFF_CTX);
    float* wcmb = (float*)(ws + OFF_WCMB);
    int*   flag = (int*)(ws + OFF_FLAG);
    float* part = (float*)(ws + OFF_PART);
    float* out  = (float*)d_out;

    hipMemsetAsync(cnt, 0, (size_t)B_ * N_ * 4, stream);
    k_maskdetect<<<1, 1, 0, stream>>>((const unsigned int*)mask, flag);
    k_embed<<<4096, 256, 0, stream>>>(gn, wnod, bnod, hb16);
    k_count<<<5000, 256, 0, stream>>>(links, cnt);
    k_scan<<<B_, 1024, 0, stream>>>(cnt, offs, pos);
    k_fill<<<5000, 256, 0, stream>>>(links, pos, epair);

    for (int l = 0; l < 2; ++l) {
        const float* mwl = msgw + (size_t)l * 128 * 64;
        const float* mbl = msgb + (size_t)l * 64;
        const float* uwl = updw + (size_t)l * 128 * 64;
        const float* ubl = updb + (size_t)l * 64;
        k_tdst_mfma<<<512, 256, 0, stream>>>(hb16, mwl, mbl, tdb);
        hipMemsetAsync(agg, 0, HB, stream);
        k_edge_mfma<<<5000, 256, 0, stream>>>(hb16, tdb, epair, mwl, agg);
        k_upd_mfma<<<512, 256, 0, stream>>>(hb16, agg, uwl, ubl);
    }

    k_aq<<<B_, 64, 0, stream>>>(ad, wad, bad, wq, bq, avec, qvec);
    k_kv_mfma<<<512, 256, 0, stream>>>(hb16, wk, bk, wv, bv, kb16, vb16);
    k_attn<<<B_ * HEADS_ * NCH, 256, 0, stream>>>(qvec, kb16, vb16, part);
    k_comb<<<B_ * HEADS_, 64, 0, stream>>>(part, ctx);
    k_g<<<B_, 64, 0, stream>>>(avec, ctx, wo, bo, lng, lnb, pw, wcmb);
    k_final<<<(B_ * N_ + 255) / 256, 256, 0, stream>>>(hb16, wcmb, pb, mask, flag, out);
}